// Round 13
// baseline (546.641 us; speedup 1.0000x reference)
//
#include <hip/hip_runtime.h>
#include <hip/hip_bf16.h>

#define B_   512
#define N_   128
#define H_   256
#define NH_  8
#define HD_  32
#define DEG_ 8
#define R_   (B_ * N_)          // 65536 rows
#define E_   (B_ * N_ * DEG_)   // 524288 edges
#define EPG_ (N_ * DEG_)        // 1024 edges per graph

typedef unsigned short u16;
typedef unsigned int u32;

typedef __attribute__((ext_vector_type(8))) short s16x8;   // 8 bf16 = 4 VGPRs
typedef __attribute__((ext_vector_type(4))) float f32x4;   // MFMA acc

__device__ __forceinline__ float b2f(u16 u) {
  union { u32 i; float f; } v;
  v.i = ((u32)u) << 16;
  return v.f;
}
__device__ __forceinline__ u16 f2b(float f) {
  union { float f; u32 u; } v;
  v.f = f;
  u32 r = (v.u + 0x7fffu + ((v.u >> 16) & 1u)) >> 16;  // RNE
  return (u16)r;
}
__device__ __forceinline__ void ld4b(const u16* p, float* o) {
  ushort4 v = *(const ushort4*)p;
  o[0] = b2f(v.x); o[1] = b2f(v.y); o[2] = b2f(v.z); o[3] = b2f(v.w);
}

// ---------------------------------------------------------------------------
// Tiled-swizzled layout for ALL 256-col bf16 intermediates:
//   [rowblk=row>>7][kstep=col>>6][row&127][seg: ((col>>3)&7)^(row&7)][col&7]
// ---------------------------------------------------------------------------
__device__ __forceinline__ int tix(int row, int col) {
  return ((row >> 7) << 15) + (((col >> 6) & 3) << 13) + ((row & 127) << 6) +
         (((((col >> 3) & 7) ^ (row & 7))) << 3) + (col & 7);
}

__device__ __forceinline__ void glds16(const u16* g, u16* l) {
  __builtin_amdgcn_global_load_lds(
      (const __attribute__((address_space(1))) void*)g,
      (__attribute__((address_space(3))) void*)l, 16, 0, 0);
}

// stats layout (floats, at d_ws + 0):
//   0..255 sum_local | 256..511 sq_local | 512..767 sum_attn | 768..1023 sq_attn
//   1024..1279 sum_out | 1280..1535 sq_out

// packed bf16 weight area offsets (u16 elements)
#define OFF_GW1 0
#define OFF_GB1 65536
#define OFF_GW2 65792
#define OFF_GB2 131328
#define OFF_AIW 131584
#define OFF_AIB 328192
#define OFF_AOW 328960
#define OFF_AOB 394496
#define OFF_F1W 394752
#define OFF_F1B 525824
#define OFF_F2W 526336
#define OFF_F2B 657408
#define W_TOTAL 657664

// ---------------------------------------------------------------------------
// prep: cvt_h (blocks 0..16383) + cvt_w (16384..17026) + zero stats (17027..)
// ---------------------------------------------------------------------------
__global__ __launch_bounds__(256) void prep_kernel(
    const float* __restrict__ hsrc, u16* __restrict__ hdst,
    const float* s0, const float* s1, const float* s2, const float* s3,
    const float* s4, const float* s5, const float* s6, const float* s7,
    const float* s8, const float* s9, const float* s10, const float* s11,
    u16* __restrict__ wdst, float* __restrict__ stats) {
  const int b = blockIdx.x, t = threadIdx.x;
  if (b < 16384) {
    const int e = (b * 256 + t) * 4;
    const float4 v = *(const float4*)(hsrc + e);
    ushort4 o;
    o.x = f2b(v.x); o.y = f2b(v.y); o.z = f2b(v.z); o.w = f2b(v.w);
    *(ushort4*)(hdst + tix(e >> 8, e & 255)) = o;
  } else if (b < 16384 + 643) {
    const int sizes[12] = {65536, 256, 65536, 256, 196608, 768,
                           65536, 256, 131072, 512, 131072, 256};
    const float* srcs[12] = {s0, s1, s2, s3, s4, s5, s6, s7, s8, s9, s10, s11};
    int gid = ((b - 16384) * 256 + t) * 4;
    if (gid >= W_TOTAL) return;
    int seg = 0, off = gid;
    while (off >= sizes[seg]) { off -= sizes[seg]; seg++; }
    const float4 v = *(const float4*)(srcs[seg] + off);
    ushort4 o;
    o.x = f2b(v.x); o.y = f2b(v.y); o.z = f2b(v.z); o.w = f2b(v.w);
    *(ushort4*)(wdst + gid) = o;
  } else {
    stats[(b - (16384 + 643)) * 256 + t] = 0.f;
  }
}

// ---------------------------------------------------------------------------
// MFMA bf16 GEMM, 64x64 tile / BK=64 / 4 waves (2x2, wave-tile 32x32).
// EXACT round-5 body. Grid dim3(NCT, 1024), col-tile fastest (L2 reuse).
// ---------------------------------------------------------------------------
template <int NC, int K, int RELU, int RES, int STATS, int ASPLIT, int CMODE>
__global__ __launch_bounds__(256) void gemm_mfma(
    const u16* A, const u16* A2,
    const u16* __restrict__ W, const u16* __restrict__ bias,
    const u16* res, u16* C0, u16* C1, u16* C2,
    float* __restrict__ gsum, float* __restrict__ gsq) {
  __shared__ u16 As[2][64 * 64] __attribute__((aligned(16)));   // 8 KB each
  __shared__ u16 Bs[2][64 * 64] __attribute__((aligned(16)));

  const int t = threadIdx.x;
  const int wave = t >> 6, lane = t & 63;
  const int wr = wave >> 1, wc = wave & 1;
  const int quad = lane >> 4, ln15 = lane & 15;
  const int row0 = blockIdx.y * 64, col0 = blockIdx.x * 64;

  f32x4 acc[2][2];
#pragma unroll
  for (int i = 0; i < 2; i++)
#pragma unroll
    for (int j = 0; j < 2; j++) acc[i][j] = (f32x4){0.f, 0.f, 0.f, 0.f};

  auto stage = [&](int b, int kt) {
    const u16* Ab;
    int ksl;
    if (ASPLIT) {
      if (kt < 256) { Ab = A; ksl = kt >> 6; } else { Ab = A2; ksl = (kt - 256) >> 6; }
    } else {
      Ab = A; ksl = kt >> 6;
    }
    const u16* abase = Ab + ((size_t)(row0 >> 7) << 15) + (ksl << 13) +
                       ((row0 & 64) << 6);
#pragma unroll
    for (int i = 0; i < 2; i++) {
      const int fid = t + i * 256;            // 0..511
      glds16(abase + fid * 8, &As[b][fid * 8]);
      const int row = fid >> 3;               // 0..63 (C col)
      const int segp = (fid & 7) ^ (row & 7);
      glds16(W + (size_t)(col0 + row) * K + kt + segp * 8, &Bs[b][fid * 8]);
    }
  };

  stage(0, 0);
  for (int kt = 0; kt < K; kt += 64) {
    const int cur = (kt >> 6) & 1;
    if (kt + 64 < K) {
      stage(cur ^ 1, kt + 64);
      asm volatile("s_waitcnt vmcnt(4)" ::: "memory");
    } else {
      asm volatile("s_waitcnt vmcnt(0)" ::: "memory");
    }
    __builtin_amdgcn_s_barrier();
#pragma unroll
    for (int ks = 0; ks < 64; ks += 32) {
      s16x8 af[2], bf[2];
#pragma unroll
      for (int i = 0; i < 2; i++) {
        const int ra = wr * 32 + i * 16 + ln15;
        af[i] = *(const s16x8*)(
            &As[cur][ra * 64 + ((((ks >> 3) + quad) ^ (ra & 7)) * 8)]);
      }
#pragma unroll
      for (int j = 0; j < 2; j++) {
        const int rb = wc * 32 + j * 16 + ln15;
        bf[j] = *(const s16x8*)(
            &Bs[cur][rb * 64 + ((((ks >> 3) + quad) ^ (rb & 7)) * 8)]);
      }
#pragma unroll
      for (int i = 0; i < 2; i++)
#pragma unroll
        for (int j = 0; j < 2; j++)
          acc[i][j] = __builtin_amdgcn_mfma_f32_16x16x32_bf16(af[i], bf[j], acc[i][j], 0, 0, 0);
    }
    __builtin_amdgcn_s_barrier();
  }

  // ---- epilogue (tiled C / res) ----
  const int cbase = col0 + wc * 32;
  u16* Cb;
  int coff;
  if (CMODE) {
    const int chunk = col0 >> 8;
    Cb = (chunk == 0) ? C0 : ((chunk == 1) ? C1 : C2);
    coff = (col0 & 255) + wc * 32;
  } else {
    Cb = C0; coff = cbase;
  }

  float bs[2];
#pragma unroll
  for (int j = 0; j < 2; j++) bs[j] = b2f(bias[cbase + j * 16 + ln15]);

  float ssum[2] = {}, ssq[2] = {};
#pragma unroll
  for (int i = 0; i < 2; i++) {
    const int rbase = row0 + wr * 32 + i * 16 + quad * 4;
#pragma unroll
    for (int reg = 0; reg < 4; reg++) {
      const int row = rbase + reg;
#pragma unroll
      for (int j = 0; j < 2; j++) {
        float val = acc[i][j][reg] + bs[j];
        if (RELU) val = fmaxf(val, 0.f);
        if (RES) val += b2f(res[tix(row, cbase + j * 16 + ln15)]);
        Cb[tix(row, coff + j * 16 + ln15)] = f2b(val);
        if (STATS) { ssum[j] += val; ssq[j] += val * val; }
      }
    }
  }

  if (STATS) {
#pragma unroll
    for (int j = 0; j < 2; j++) {
      float s = ssum[j];
      s += __shfl_xor(s, 16);
      s += __shfl_xor(s, 32);
      float q = ssq[j];
      q += __shfl_xor(q, 16);
      q += __shfl_xor(q, 32);
      if (lane < 16) {
        atomicAdd(&gsum[cbase + j * 16 + lane], s);
        atomicAdd(&gsq[cbase + j * 16 + lane], q);
      }
    }
  }
}

// ---------------------------------------------------------------------------
// QKV GEMM (r12, kept): one block computes q, k AND v 64-col tiles; A staged
// once. Grid dim3(4, 1024). LDS As 16K + Bs 48K = 64 KB -> 2 blocks/CU.
// ---------------------------------------------------------------------------
__global__ __launch_bounds__(256) void qkv_mfma(
    const u16* A, const u16* __restrict__ W, const u16* __restrict__ bias,
    u16* Cq, u16* Ck, u16* Cv) {
  __shared__ u16 As[2][64 * 64] __attribute__((aligned(16)));      // 16 KB
  __shared__ u16 Bs[2][3 * 64 * 64] __attribute__((aligned(16)));  // 48 KB

  const int t = threadIdx.x;
  const int wave = t >> 6, lane = t & 63;
  const int wr = wave >> 1, wc = wave & 1;
  const int quad = lane >> 4, ln15 = lane & 15;
  const int row0 = blockIdx.y * 64, col0 = blockIdx.x * 64;

  f32x4 acc[3][2][2];
#pragma unroll
  for (int o = 0; o < 3; o++)
#pragma unroll
    for (int i = 0; i < 2; i++)
#pragma unroll
      for (int j = 0; j < 2; j++) acc[o][i][j] = (f32x4){0.f, 0.f, 0.f, 0.f};

  auto stage = [&](int b, int kt) {
    const u16* abase = A + ((size_t)(row0 >> 7) << 15) + ((kt >> 6) << 13) +
                       ((row0 & 64) << 6);
#pragma unroll
    for (int i = 0; i < 2; i++) {
      const int fid = t + i * 256;            // 0..511
      glds16(abase + fid * 8, &As[b][fid * 8]);
    }
#pragma unroll
    for (int o = 0; o < 3; o++)
#pragma unroll
      for (int i = 0; i < 2; i++) {
        const int fid = t + i * 256;
        const int row = fid >> 3;             // 0..63 (output col)
        const int segp = (fid & 7) ^ (row & 7);
        glds16(W + (size_t)(o * 256 + col0 + row) * 256 + kt + segp * 8,
               &Bs[b][o * 4096 + fid * 8]);
      }
  };

  stage(0, 0);
  for (int kt = 0; kt < 256; kt += 64) {
    const int cur = (kt >> 6) & 1;
    if (kt + 64 < 256) {
      stage(cur ^ 1, kt + 64);
      asm volatile("s_waitcnt vmcnt(8)" ::: "memory");
    } else {
      asm volatile("s_waitcnt vmcnt(0)" ::: "memory");
    }
    __builtin_amdgcn_s_barrier();
#pragma unroll
    for (int ks = 0; ks < 64; ks += 32) {
      s16x8 af[2];
#pragma unroll
      for (int i = 0; i < 2; i++) {
        const int ra = wr * 32 + i * 16 + ln15;
        af[i] = *(const s16x8*)(
            &As[cur][ra * 64 + ((((ks >> 3) + quad) ^ (ra & 7)) * 8)]);
      }
#pragma unroll
      for (int o = 0; o < 3; o++) {
        s16x8 bf[2];
#pragma unroll
        for (int j = 0; j < 2; j++) {
          const int rb = wc * 32 + j * 16 + ln15;
          bf[j] = *(const s16x8*)(
              &Bs[cur][o * 4096 + rb * 64 + ((((ks >> 3) + quad) ^ (rb & 7)) * 8)]);
        }
#pragma unroll
        for (int i = 0; i < 2; i++)
#pragma unroll
          for (int j = 0; j < 2; j++)
            acc[o][i][j] = __builtin_amdgcn_mfma_f32_16x16x32_bf16(af[i], bf[j], acc[o][i][j], 0, 0, 0);
      }
    }
    __builtin_amdgcn_s_barrier();
  }

  const int cbase = col0 + wc * 32;
#pragma unroll
  for (int o = 0; o < 3; o++) {
    u16* Co = (o == 0) ? Cq : ((o == 1) ? Ck : Cv);
    float bs[2];
#pragma unroll
    for (int j = 0; j < 2; j++) bs[j] = b2f(bias[o * 256 + cbase + j * 16 + ln15]);
#pragma unroll
    for (int i = 0; i < 2; i++) {
      const int rbase = row0 + wr * 32 + i * 16 + quad * 4;
#pragma unroll
      for (int reg = 0; reg < 4; reg++) {
        const int row = rbase + reg;
#pragma unroll
        for (int j = 0; j < 2; j++)
          Co[tix(row, cbase + j * 16 + ln15)] = f2b(acc[o][i][j][reg] + bs[j]);
      }
    }
  }
}

// ---------------------------------------------------------------------------
// Fused 2-layer MLP (r13 = r10 body + GATHER/COMBINE x-stage variants):
//   GATHER=1:  x = h + segment_sum(h[src], dst)  -- agg folded in; CSR built
//              in the dead tc region, gather writes xs in the glds16-identical
//              swizzled layout (same f2b rounding -> bit-identical z).
//   COMBINE=1: x = bn_l(A)+bn_a(Ara); BN coefficients computed IN-KERNEL from
//              raw stats sums (bn_finalize folded in; identical fp32 math).
//   else:      x = A via glds16 (r8-verified path).
//   C = x + relu(x@W1^T + b1)@W2^T + b2 (+res), + stats.
// r9: weights MUST stage via wave-linear glds16. r11: deeper W pipelining
// NEUTRAL -> keep the simple r10 schedule. LDS 80 KB -> 2 blocks/CU.
// ---------------------------------------------------------------------------
template <int CHUNKS, int RES_LDS, int COMBINE, int GATHER>
__global__ __launch_bounds__(256, 2) void fused_mlp(
    const u16* A, const u16* Ara,
    const int* __restrict__ esrc, const int* __restrict__ edst,
    const u16* __restrict__ W1, const u16* __restrict__ b1,
    const u16* __restrict__ W2, const u16* __restrict__ b2,
    const u16* resg, u16* C, const float* __restrict__ st,
    const float* __restrict__ bn0g, const float* __restrict__ bn0b,
    const float* __restrict__ bn1g, const float* __restrict__ bn1b,
    float* __restrict__ gsum, float* __restrict__ gsq) {
  __shared__ u16 xs[4 * 64 * 64] __attribute__((aligned(16)));    // 32 KB
  __shared__ u16 tc[64 * 128] __attribute__((aligned(16)));       // 16 KB
  __shared__ u16 Wst[2][128 * 64] __attribute__((aligned(16)));   // 32 KB

  const int t = threadIdx.x;
  const int wave = t >> 6, lane = t & 63;
  const int wr = wave >> 1, wc = wave & 1;
  const int quad = lane >> 4, ln15 = lane & 15;
  const int row0 = blockIdx.x * 64;
  const int K2 = CHUNKS * 128;   // W2 row stride

  // ---- stage x rows row0..+63, all 256 cols ----
  if (GATHER) {
    // CSR overlay in tc (dead until chunk 0): src 4K | cnt | off | pos
    int* s_srcp = (int*)tc;                // 1024 ints
    int* s_cntp = (int*)(tc + 2048);       // 64
    int* s_offp = (int*)(tc + 2304);       // 65
    int* s_posp = (int*)(tc + 2560);       // 64
    if (t < 64) s_cntp[t] = 0;
    __syncthreads();
    const int g = row0 >> 7;
    const int r0l = row0 & 64;
    const int ebase = g * EPG_;
    int dl[4], sv[4];
#pragma unroll
    for (int i = 0; i < 4; i++) {
      const int e = ebase + t + i * 256;
      sv[i] = esrc[e];
      dl[i] = edst[e] - g * N_ - r0l;
      if ((unsigned)dl[i] < 64u) atomicAdd(&s_cntp[dl[i]], 1);
    }
    __syncthreads();
    if (t == 0) {
      int a = 0;
#pragma unroll
      for (int i = 0; i < 64; i++) { s_offp[i] = a; a += s_cntp[i]; }
      s_offp[64] = a;
    }
    __syncthreads();
    if (t < 64) s_posp[t] = s_offp[t];
    __syncthreads();
#pragma unroll
    for (int i = 0; i < 4; i++) {
      if ((unsigned)dl[i] < 64u) {
        const int slot = atomicAdd(&s_posp[dl[i]], 1);
        s_srcp[slot] = sv[i];
      }
    }
    __syncthreads();
    // gather: 8 row-groups x 32 lanes; lane owns 8 logical cols c0..c0+7
    const int rg = t >> 5;
    const int c0 = (t & 31) * 8;
    const int panel = c0 >> 6;
    const int segi = (c0 >> 3) & 7;
    for (int ib = 0; ib < 64; ib += 8) {
      const int rowl = ib + rg;
      float acc[8];
      {
        const s16x8 v = *(const s16x8*)(A + tix(row0 + rowl, c0));
#pragma unroll
        for (int j = 0; j < 8; j++) acc[j] = b2f((u16)v[j]);
      }
      const int e0 = s_offp[rowl], e1 = s_offp[rowl + 1];
      for (int e = e0; e < e1; e++) {
        const s16x8 v = *(const s16x8*)(A + tix(s_srcp[e], c0));
#pragma unroll
        for (int j = 0; j < 8; j++) acc[j] += b2f((u16)v[j]);
      }
      s16x8 o;
#pragma unroll
      for (int j = 0; j < 8; j++) o[j] = (short)f2b(acc[j]);
      *(s16x8*)(xs + panel * 4096 + rowl * 64 + ((segi ^ (rowl & 7)) << 3)) = o;
    }
    __syncthreads();   // xs ready; tc free for chunk 0
  } else if (COMBINE) {
    // bn_finalize folded: compute al|bl|aa|ba from raw sums -> cf (tc region)
    float* cf = (float*)tc;
    {
      const float ml = st[t] * (1.f / R_);
      const float vl = fmaxf(st[256 + t] * (1.f / R_) - ml * ml, 0.f);
      const float al = bn0g[t] * rsqrtf(vl + 1e-5f);
      cf[t] = al;
      cf[256 + t] = bn0b[t] - ml * al;
      const float ma = st[512 + t] * (1.f / R_);
      const float va = fmaxf(st[768 + t] * (1.f / R_) - ma * ma, 0.f);
      const float aa = bn1g[t] * rsqrtf(va + 1e-5f);
      cf[512 + t] = aa;
      cf[768 + t] = bn1b[t] - ma * aa;
    }
    __syncthreads();
    const size_t tbase = ((size_t)(row0 >> 7) << 15) + ((row0 & 64) << 6);
#pragma unroll
    for (int i = 0; i < 8; i++) {
      const int gid = t + i * 256;        // 0..2047 16B-chunks
      const int kstep = gid >> 9;
      const int fid = gid & 511;
      const size_t addr = tbase + kstep * 8192 + fid * 8;
      const s16x8 rl = *(const s16x8*)(A + addr);
      const s16x8 ra = *(const s16x8*)(Ara + addr);
      const int seg = (fid & 7) ^ ((fid >> 3) & 7);
      const int col = kstep * 64 + seg * 8;
      const float4 al0 = *(const float4*)(cf + col);
      const float4 al1 = *(const float4*)(cf + col + 4);
      const float4 bl0 = *(const float4*)(cf + 256 + col);
      const float4 bl1 = *(const float4*)(cf + 256 + col + 4);
      const float4 aa0 = *(const float4*)(cf + 512 + col);
      const float4 aa1 = *(const float4*)(cf + 512 + col + 4);
      const float4 ba0 = *(const float4*)(cf + 768 + col);
      const float4 ba1 = *(const float4*)(cf + 768 + col + 4);
      const float al[8] = {al0.x, al0.y, al0.z, al0.w, al1.x, al1.y, al1.z, al1.w};
      const float bl[8] = {bl0.x, bl0.y, bl0.z, bl0.w, bl1.x, bl1.y, bl1.z, bl1.w};
      const float aa[8] = {aa0.x, aa0.y, aa0.z, aa0.w, aa1.x, aa1.y, aa1.z, aa1.w};
      const float ba[8] = {ba0.x, ba0.y, ba0.z, ba0.w, ba1.x, ba1.y, ba1.z, ba1.w};
      s16x8 o;
#pragma unroll
      for (int j = 0; j < 8; j++)
        o[j] = (short)f2b(al[j] * b2f((u16)rl[j]) + bl[j] +
                          aa[j] * b2f((u16)ra[j]) + ba[j]);
      *(s16x8*)(xs + gid * 8) = o;
    }
    __syncthreads();   // xs ready; tc coeffs dead, reusable
  } else {
    const u16* abase = A + ((size_t)(row0 >> 7) << 15) + ((row0 & 64) << 6);
#pragma unroll
    for (int i = 0; i < 8; i++) {
      const int gid = t + i * 256;        // 0..2047 16B-loads
      const int kstep = gid >> 9;
      const int fid = gid & 511;
      glds16(abase + kstep * 8192 + fid * 8, xs + gid * 8);
    }
  }

  f32x4 acc2[2][8];
#pragma unroll
  for (int i = 0; i < 2; i++)
#pragma unroll
    for (int j = 0; j < 8; j++) acc2[i][j] = (f32x4){0.f, 0.f, 0.f, 0.f};

  // t-chunk LDS addressing: conflict-free column-slice b128 reads
  auto tca = [&](int row, int col) {
    const int s0 = col >> 3;
    return row * 128 + (((s0 & 8) | ((s0 ^ row) & 7)) << 3) + (col & 7);
  };

  for (int c = 0; c < CHUNKS; c++) {
    // ================= GEMM1: tchunk = relu(x @ W1[c*128..+128]^T) =========
    f32x4 acc1[2][4];
#pragma unroll
    for (int i = 0; i < 2; i++)
#pragma unroll
      for (int j = 0; j < 4; j++) acc1[i][j] = (f32x4){0.f, 0.f, 0.f, 0.f};

    auto stage1 = [&](int b, int kt) {
#pragma unroll
      for (int i = 0; i < 4; i++) {
        const int fid = t + i * 256;      // 0..1023
        const int row = fid >> 3;         // 0..127
        const int segp = (fid & 7) ^ (row & 7);
        glds16(W1 + (size_t)(c * 128 + row) * 256 + kt + segp * 8,
               &Wst[b][fid * 8]);
      }
    };

    stage1(0, 0);
    for (int kt = 0; kt < 256; kt += 64) {
      const int cur = (kt >> 6) & 1;
      if (kt + 64 < 256) {
        stage1(cur ^ 1, kt + 64);
        asm volatile("s_waitcnt vmcnt(4)" ::: "memory");
      } else {
        asm volatile("s_waitcnt vmcnt(0)" ::: "memory");
      }
      __builtin_amdgcn_s_barrier();
#pragma unroll
      for (int ks = 0; ks < 64; ks += 32) {
        s16x8 af[2], bf[4];
#pragma unroll
        for (int i = 0; i < 2; i++) {
          const int ra = wr * 32 + i * 16 + ln15;
          af[i] = *(const s16x8*)(
              &xs[(kt >> 6) * 4096 + ra * 64 +
                  ((((ks >> 3) + quad) ^ (ra & 7)) * 8)]);
        }
#pragma unroll
        for (int j = 0; j < 4; j++) {
          const int rb = wc * 64 + j * 16 + ln15;
          bf[j] = *(const s16x8*)(
              &Wst[cur][rb * 64 + ((((ks >> 3) + quad) ^ (rb & 7)) * 8)]);
        }
#pragma unroll
        for (int i = 0; i < 2; i++)
#pragma unroll
          for (int j = 0; j < 4; j++)
            acc1[i][j] = __builtin_amdgcn_mfma_f32_16x16x32_bf16(af[i], bf[j], acc1[i][j], 0, 0, 0);
      }
      __builtin_amdgcn_s_barrier();
    }

    // relu + bias -> tc (bf16)
    {
      float b1s[4];
#pragma unroll
      for (int j = 0; j < 4; j++)
        b1s[j] = b2f(b1[c * 128 + wc * 64 + j * 16 + ln15]);
#pragma unroll
      for (int i = 0; i < 2; i++)
#pragma unroll
        for (int reg = 0; reg < 4; reg++) {
          const int rowl = wr * 32 + i * 16 + quad * 4 + reg;
#pragma unroll
          for (int j = 0; j < 4; j++) {
            const int coll = wc * 64 + j * 16 + ln15;
            tc[tca(rowl, coll)] = f2b(fmaxf(acc1[i][j][reg] + b1s[j], 0.f));
          }
        }
    }
    __syncthreads();   // tc ready; Wst free

    // ================= GEMM2: acc2 += tchunk @ W2[:, c*128..+128]^T ========
    for (int ks2 = 0; ks2 < 2; ks2++) {
#pragma unroll
      for (int i = 0; i < 8; i++) {
        const int fid = t + i * 256;      // 0..2047
        const int row = fid >> 3;         // 0..255
        const int segp = (fid & 7) ^ (row & 7);
        glds16(W2 + (size_t)row * K2 + c * 128 + ks2 * 64 + segp * 8,
               &Wst[0][fid * 8]);
      }
      asm volatile("s_waitcnt vmcnt(0)" ::: "memory");
      __builtin_amdgcn_s_barrier();
#pragma unroll
      for (int ksl = 0; ksl < 64; ksl += 32) {
        s16x8 af[2], bf[8];
#pragma unroll
        for (int i = 0; i < 2; i++) {
          const int ra = wr * 32 + i * 16 + ln15;
          af[i] = *(const s16x8*)(&tc[tca(ra, ks2 * 64 + ksl + quad * 8)]);
        }
#pragma unroll
        for (int j = 0; j < 8; j++) {
          const int rb = wc * 128 + j * 16 + ln15;
          bf[j] = *(const s16x8*)(
              &Wst[0][rb * 64 + ((((ksl >> 3) + quad) ^ (rb & 7)) * 8)]);
        }
#pragma unroll
        for (int i = 0; i < 2; i++)
#pragma unroll
          for (int j = 0; j < 8; j++)
            acc2[i][j] = __builtin_amdgcn_mfma_f32_16x16x32_bf16(af[i], bf[j], acc2[i][j], 0, 0, 0);
      }
      __builtin_amdgcn_s_barrier();
    }
  }

  // ---- epilogue: y = acc2 + b2 + res -> C (tiled) + stats ----
  float bs2[8];
#pragma unroll
  for (int j = 0; j < 8; j++)
    bs2[j] = b2f(b2[wc * 128 + j * 16 + ln15]);

  float ssum[8] = {}, ssq[8] = {};
#pragma unroll
  for (int i = 0; i < 2; i++) {
#pragma unroll
    for (int reg = 0; reg < 4; reg++) {
      const int rowl = wr * 32 + i * 16 + quad * 4 + reg;
      const int row = row0 + rowl;
#pragma unroll
      for (int j = 0; j < 8; j++) {
        const int col = wc * 128 + j * 16 + ln15;
        float val = acc2[i][j][reg] + bs2[j];
        if (RES_LDS) {
          val += b2f(xs[(col >> 6) * 4096 + rowl * 64 +
                        ((((col >> 3) & 7) ^ (rowl & 7)) << 3) + (col & 7)]);
        } else {
          val += b2f(resg[tix(row, col)]);
        }
        C[tix(row, col)] = f2b(val);
        ssum[j] += val; ssq[j] += val * val;
      }
    }
  }

#pragma unroll
  for (int j = 0; j < 8; j++) {
    float s = ssum[j];
    s += __shfl_xor(s, 16);
    s += __shfl_xor(s, 32);
    float q = ssq[j];
    q += __shfl_xor(q, 16);
    q += __shfl_xor(q, 32);
    if (lane < 16) {
      atomicAdd(&gsum[wc * 128 + j * 16 + lane], s);
      atomicAdd(&gsq[wc * 128 + j * 16 + lane], q);
    }
  }
}

// ---------------------------------------------------------------------------
// MFMA attention: one block per (graph, head), 4 waves; q/k/v/o tiled (tix).
// ---------------------------------------------------------------------------
__global__ __launch_bounds__(256) void attn_mfma(
    const u16* q, const u16* __restrict__ k,
    const u16* __restrict__ v, u16* o) {
  __shared__ u16 lds[21760] __attribute__((aligned(16)));
  u16* Vt = lds;                   // [32][136]  V transposed (d-major)
  u16* Qs = lds + 4352;            // [128][40]  scaled Q
  u16* Ks = lds + 4352 + 5120;     // [128][40]
  u16* P  = lds + 4352;            // [128][136] aliases Qs/Ks after barrier

  const int g = blockIdx.x >> 3;
  const int hd = blockIdx.x & 7;
  const int t = threadIdx.x;
  const int wave = t >> 6, lane = t & 63;
  const int quad = lane >> 4, ln15 = lane & 15;
  const int strip = wave * 32;
  const float scale = 0.1767766952966369f;  // 1/sqrt(32)

  // ---- stage Q (pre-scaled), K, V^T ----
#pragma unroll
  for (int i = 0; i < 4; i++) {
    const int fid = t + i * 256;   // 0..1023
    const int row = fid >> 3;
    const int seg = fid & 7;       // 4 u16 each
    const int gidx = tix(g * N_ + row, hd * HD_ + seg * 4);
    const ushort4 qv = *(const ushort4*)(q + gidx);
    const ushort4 kv = *(const ushort4*)(k + gidx);
    const ushort4 vv = *(const ushort4*)(v + gidx);
    ushort4 qs;
    qs.x = f2b(b2f(qv.x) * scale); qs.y = f2b(b2f(qv.y) * scale);
    qs.z = f2b(b2f(qv.z) * scale); qs.w = f2b(b2f(qv.w) * scale);
    *(ushort4*)(Qs + row * 40 + seg * 4) = qs;
    *(ushort4*)(Ks + row * 40 + seg * 4) = kv;
    Vt[(seg * 4 + 0) * 136 + row] = vv.x;
    Vt[(seg * 4 + 1) * 136 + row] = vv.y;
    Vt[(seg * 4 + 2) * 136 + row] = vv.z;
    Vt[(seg * 4 + 3) * 136 + row] = vv.w;
  }
  __syncthreads();

  // ---- S = Q K^T (strip x 128) ----
  s16x8 af[2], bf[8];
#pragma unroll
  for (int mi = 0; mi < 2; mi++)
    af[mi] = *(const s16x8*)(Qs + (strip + mi * 16 + ln15) * 40 + quad * 8);
#pragma unroll
  for (int nj = 0; nj < 8; nj++)
    bf[nj] = *(const s16x8*)(Ks + (nj * 16 + ln15) * 40 + quad * 8);

  f32x4 acc[2][8];
#pragma unroll
  for (int mi = 0; mi < 2; mi++)
#pragma unroll
    for (int nj = 0; nj < 8; nj++)
      acc[mi][nj] = __builtin_amdgcn_mfma_f32_16x16x32_bf16(
          af[mi], bf[nj], (f32x4){0.f, 0.f, 0.f, 0.f}, 0, 0, 0);

  __syncthreads();  // Q/K dead; region becomes P

  // ---- softmax per row, write P ----
#pragma unroll
  for (int mi = 0; mi < 2; mi++) {
#pragma unroll
    for (int reg = 0; reg < 4; reg++) {
      float mx = acc[mi][0][reg];
#pragma unroll
      for (int j = 1; j < 8; j++) mx = fmaxf(mx, acc[mi][j][reg]);
      mx = fmaxf(mx, __shfl_xor(mx, 1));
      mx = fmaxf(mx, __shfl_xor(mx, 2));
      mx = fmaxf(mx, __shfl_xor(mx, 4));
      mx = fmaxf(mx, __shfl_xor(mx, 8));
      float e[8], s = 0.f;
#pragma unroll
      for (int j = 0; j < 8; j++) { e[j] = __expf(acc[mi][j][reg] - mx); s += e[j]; }
      s += __shfl_xor(s, 1);
      s += __shfl_xor(s, 2);
      s += __shfl_xor(s, 4);
      s += __shfl_xor(s, 8);
      const float inv = 1.f / s;
      const int prow = strip + mi * 16 + quad * 4 + reg;
#pragma unroll
      for (int j = 0; j < 8; j++)
        P[prow * 136 + j * 16 + ln15] = f2b(e[j] * inv);
    }
  }
  __syncthreads();

  // ---- O = P V (strip x 32) ----
  f32x4 acc2[2][2];
#pragma unroll
  for (int mi = 0; mi < 2; mi++)
#pragma unroll
    for (int nj = 0; nj < 2; nj++) acc2[mi][nj] = (f32x4){0.f, 0.f, 0.f, 0.f};
#pragma unroll
  for (int kt = 0; kt < 4; kt++) {
    s16x8 paf[2], vbf[2];
#pragma unroll
    for (int mi = 0; mi < 2; mi++)
      paf[mi] = *(const s16x8*)(P + (strip + mi * 16 + ln15) * 136 + kt * 32 + quad * 8);
#pragma unroll
    for (int nj = 0; nj < 2; nj++)
      vbf[nj] = *(const s16x8*)(Vt + (nj * 16 + ln15) * 136 + kt * 32 + quad * 8);
#pragma unroll
    for (int mi = 0; mi < 2; mi++)
#pragma unroll
      for (int nj = 0; nj < 2; nj++)
        acc2[mi][nj] = __builtin_amdgcn_mfma_f32_16x16x32_bf16(
            paf[mi], vbf[nj], acc2[mi][nj], 0, 0, 0);
  }

#pragma unroll
  for (int mi = 0; mi < 2; mi++)
#pragma unroll
    for (int nj = 0; nj < 2; nj++)
#pragma unroll
      for (int reg = 0; reg < 4; reg++) {
        const int row = strip + mi * 16 + quad * 4 + reg;
        o[tix(g * N_ + row, hd * HD_ + nj * 16 + ln15)] =
            f2b(acc2[mi][nj][reg]);
      }
}

// out = bn_out(y) with bn_finalize folded: per-thread coefficient compute.
__global__ __launch_bounds__(256) void final_kernel(
    const u16* __restrict__ y, const float* __restrict__ st,
    const float* __restrict__ bg, const float* __restrict__ bb,
    float* __restrict__ out) {
  const int e = (blockIdx.x * 256 + threadIdx.x) * 4;
  const int col = e & 255;
  float y4[4];
  ld4b(y + tix(e >> 8, col), y4);
  const float4 s4 = *(const float4*)(st + 1024 + col);
  const float4 q4 = *(const float4*)(st + 1280 + col);
  const float4 g4 = *(const float4*)(bg + col);
  const float4 b4 = *(const float4*)(bb + col);
  const float ss[4] = {s4.x, s4.y, s4.z, s4.w};
  const float qq[4] = {q4.x, q4.y, q4.z, q4.w};
  const float gg[4] = {g4.x, g4.y, g4.z, g4.w};
  const float bv[4] = {b4.x, b4.y, b4.z, b4.w};
  float4 o;
  float* ov = (float*)&o;
#pragma unroll
  for (int j = 0; j < 4; j++) {
    const float mean = ss[j] * (1.f / R_);
    const float var = fmaxf(qq[j] * (1.f / R_) - mean * mean, 0.f);
    const float a = gg[j] * rsqrtf(var + 1e-5f);
    ov[j] = a * y4[j] + (bv[j] - mean * a);
  }
  *(float4*)(out + e) = o;
}

extern "C" void kernel_launch(void* const* d_in, const int* in_sizes, int n_in,
                              void* d_out, int out_size, void* d_ws, size_t ws_size,
                              hipStream_t stream) {
  const float* h = (const float*)d_in[0];
  const int* esrc = (const int*)d_in[1];
  const int* edst = (const int*)d_in[2];
  const float* bn_local_g = (const float*)d_in[11];
  const float* bn_local_b = (const float*)d_in[12];
  const float* bn_attn_g = (const float*)d_in[13];
  const float* bn_attn_b = (const float*)d_in[14];
  const float* bn_out_g = (const float*)d_in[15];
  const float* bn_out_b = (const float*)d_in[16];

  const size_t RH = (size_t)R_ * H_;
  float* stats = (float*)d_ws;                        // 1536 floats used
  u16* WB = (u16*)((char*)d_ws + 65536);              // packed bf16 weights ~1.3 MB
  u16* Hb = (u16*)((char*)d_ws + 65536 + 2097152);    // h in bf16 (tiled), 32 MB
  u16* S1 = Hb + RH;                                  // 32 MB
  u16* S2 = S1 + RH;                                  // 32 MB
  u16* OD = (u16*)d_out;                              // first 32 MB of d_out as bf16 scratch
  float* outf = (float*)d_out;                        // final fp32 out (64 MB)

  // cvt_h + cvt_w + zero_stats in one launch
  prep_kernel<<<16384 + 643 + 12, 256, 0, stream>>>(
      h, Hb,
      (const float*)d_in[3], (const float*)d_in[4], (const float*)d_in[5],
      (const float*)d_in[6], (const float*)d_in[7], (const float*)d_in[8],
      (const float*)d_in[9], (const float*)d_in[10], (const float*)d_in[17],
      (const float*)d_in[18], (const float*)d_in[19], (const float*)d_in[20],
      WB, stats);

  // qkv: A staged once per block for all of q,k,v -> q=S1, k=S2, v=OD
  qkv_mfma<<<dim3(4, 1024), 256, 0, stream>>>(
      Hb, WB + OFF_AIW, WB + OFF_AIB, S1, S2, OD);
  // o = softmax(q k^T / sqrt(32)) v, in-place over q (S1)
  attn_mfma<<<B_ * NH_, 256, 0, stream>>>(S1, S2, OD, S1);
  // r_attn = h + o@Wo^T -> S2, + stats_attn
  gemm_mfma<256, 256, 0, 1, 1, 0, 0><<<dim3(4, 1024), 256, 0, stream>>>(
      S1, nullptr, WB + OFF_AOW, WB + OFF_AOB, Hb, S2, nullptr, nullptr,
      stats + 512, stats + 768);
  // r_local = h + relu(z@GW1+b1)@GW2+b2 -> OD, z gathered IN-KERNEL (agg fold)
  fused_mlp<2, 0, 0, 1><<<1024, 256, 0, stream>>>(
      Hb, nullptr, esrc, edst,
      WB + OFF_GW1, WB + OFF_GB1, WB + OFF_GW2, WB + OFF_GB2,
      Hb, OD, nullptr, nullptr, nullptr, nullptr, nullptr,
      stats + 0, stats + 256);
  // y = x + relu(x@F1+b1)@F2+b2 -> S1; x = bn_l(OD)+bn_a(S2) with BN
  // coefficients computed in-kernel (combine + bn_finalize folds), + stats_out
  fused_mlp<4, 1, 1, 0><<<1024, 256, 0, stream>>>(
      OD, S2, nullptr, nullptr,
      WB + OFF_F1W, WB + OFF_F1B, WB + OFF_F2W, WB + OFF_F2B,
      nullptr, S1, stats, bn_local_g, bn_local_b, bn_attn_g, bn_attn_b,
      stats + 1024, stats + 1280);
  // out = bn_out(y S1) -> fp32 d_out (bn_finalize folded)
  final_kernel<<<(int)(RH / 4 / 256), 256, 0, stream>>>(
      S1, stats, bn_out_g, bn_out_b, outf);
}

// Round 14
// 532.516 us; speedup vs baseline: 1.0265x; 1.0265x over previous
//
#include <hip/hip_runtime.h>
#include <hip/hip_bf16.h>

#define B_   512
#define N_   128
#define H_   256
#define NH_  8
#define HD_  32
#define DEG_ 8
#define R_   (B_ * N_)          // 65536 rows
#define E_   (B_ * N_ * DEG_)   // 524288 edges
#define EPG_ (N_ * DEG_)        // 1024 edges per graph

typedef unsigned short u16;
typedef unsigned int u32;

typedef __attribute__((ext_vector_type(8))) short s16x8;   // 8 bf16 = 4 VGPRs
typedef __attribute__((ext_vector_type(4))) float f32x4;   // MFMA acc

__device__ __forceinline__ float b2f(u16 u) {
  union { u32 i; float f; } v;
  v.i = ((u32)u) << 16;
  return v.f;
}
__device__ __forceinline__ u16 f2b(float f) {
  union { float f; u32 u; } v;
  v.f = f;
  u32 r = (v.u + 0x7fffu + ((v.u >> 16) & 1u)) >> 16;  // RNE
  return (u16)r;
}
__device__ __forceinline__ void ld4b(const u16* p, float* o) {
  ushort4 v = *(const ushort4*)p;
  o[0] = b2f(v.x); o[1] = b2f(v.y); o[2] = b2f(v.z); o[3] = b2f(v.w);
}

// ---------------------------------------------------------------------------
// Tiled-swizzled layout for ALL 256-col bf16 intermediates:
//   [rowblk=row>>7][kstep=col>>6][row&127][seg: ((col>>3)&7)^(row&7)][col&7]
// ---------------------------------------------------------------------------
__device__ __forceinline__ int tix(int row, int col) {
  return ((row >> 7) << 15) + (((col >> 6) & 3) << 13) + ((row & 127) << 6) +
         (((((col >> 3) & 7) ^ (row & 7))) << 3) + (col & 7);
}

__device__ __forceinline__ void glds16(const u16* g, u16* l) {
  __builtin_amdgcn_global_load_lds(
      (const __attribute__((address_space(1))) void*)g,
      (__attribute__((address_space(3))) void*)l, 16, 0, 0);
}

// stats layout (floats, at d_ws + 0):
//   0..255 sum_local | 256..511 sq_local | 512..767 sum_attn | 768..1023 sq_attn
//   1024..1279 sum_out | 1280..1535 sq_out

// packed bf16 weight area offsets (u16 elements)
#define OFF_GW1 0
#define OFF_GB1 65536
#define OFF_GW2 65792
#define OFF_GB2 131328
#define OFF_AIW 131584
#define OFF_AIB 328192
#define OFF_AOW 328960
#define OFF_AOB 394496
#define OFF_F1W 394752
#define OFF_F1B 525824
#define OFF_F2W 526336
#define OFF_F2B 657408
#define W_TOTAL 657664

// ---------------------------------------------------------------------------
// prep: cvt_h (blocks 0..16383) + cvt_w (16384..17026) + zero stats (17027..)
// ---------------------------------------------------------------------------
__global__ __launch_bounds__(256) void prep_kernel(
    const float* __restrict__ hsrc, u16* __restrict__ hdst,
    const float* s0, const float* s1, const float* s2, const float* s3,
    const float* s4, const float* s5, const float* s6, const float* s7,
    const float* s8, const float* s9, const float* s10, const float* s11,
    u16* __restrict__ wdst, float* __restrict__ stats) {
  const int b = blockIdx.x, t = threadIdx.x;
  if (b < 16384) {
    const int e = (b * 256 + t) * 4;
    const float4 v = *(const float4*)(hsrc + e);
    ushort4 o;
    o.x = f2b(v.x); o.y = f2b(v.y); o.z = f2b(v.z); o.w = f2b(v.w);
    *(ushort4*)(hdst + tix(e >> 8, e & 255)) = o;
  } else if (b < 16384 + 643) {
    const int sizes[12] = {65536, 256, 65536, 256, 196608, 768,
                           65536, 256, 131072, 512, 131072, 256};
    const float* srcs[12] = {s0, s1, s2, s3, s4, s5, s6, s7, s8, s9, s10, s11};
    int gid = ((b - 16384) * 256 + t) * 4;
    if (gid >= W_TOTAL) return;
    int seg = 0, off = gid;
    while (off >= sizes[seg]) { off -= sizes[seg]; seg++; }
    const float4 v = *(const float4*)(srcs[seg] + off);
    ushort4 o;
    o.x = f2b(v.x); o.y = f2b(v.y); o.z = f2b(v.z); o.w = f2b(v.w);
    *(ushort4*)(wdst + gid) = o;
  } else {
    stats[(b - (16384 + 643)) * 256 + t] = 0.f;
  }
}

// ---------------------------------------------------------------------------
// Edge aggregation: z = h + segment_sum(h[src], dst).  (tiled h/z)
// Standalone high-occupancy kernel (r13 proved folding this into the
// 2-blocks/CU fused_mlp costs +34 us: latency-bound phases need occupancy).
// ---------------------------------------------------------------------------
#define SROWS_ 32   // rows per slice

__global__ __launch_bounds__(256) void agg_kernel(
    const u16* __restrict__ h, const int* __restrict__ esrc,
    const int* __restrict__ edst, u16* __restrict__ z) {
  __shared__ int s_src[EPG_];
  __shared__ int s_cnt[SROWS_];
  __shared__ int s_off[SROWS_ + 1];
  __shared__ int s_pos[SROWS_];
  const int g = blockIdx.x;
  const int r0 = blockIdx.y * SROWS_;
  const int t = threadIdx.x;

  if (t < SROWS_) s_cnt[t] = 0;
  __syncthreads();

  const int ebase = g * EPG_;
  int dl[4], sg[4];
#pragma unroll
  for (int i = 0; i < 4; i++) {
    const int e = ebase + t + i * 256;
    sg[i] = esrc[e];
    dl[i] = edst[e] - g * N_ - r0;
    if ((unsigned)dl[i] < SROWS_) atomicAdd(&s_cnt[dl[i]], 1);
  }
  __syncthreads();
  if (t == 0) {
    int acc = 0;
#pragma unroll
    for (int i = 0; i < SROWS_; i++) { s_off[i] = acc; acc += s_cnt[i]; }
    s_off[SROWS_] = acc;
  }
  __syncthreads();
  if (t < SROWS_) s_pos[t] = s_off[t];
  __syncthreads();
#pragma unroll
  for (int i = 0; i < 4; i++) {
    if ((unsigned)dl[i] < SROWS_) {
      const int slot = atomicAdd(&s_pos[dl[i]], 1);
      s_src[slot] = sg[i];
    }
  }
  __syncthreads();

  const int rg = t >> 5;
  const int c0 = (t & 31) * 8;
  for (int ib = 0; ib < SROWS_; ib += 8) {
    const int i = ib + rg;
    const int row = g * N_ + r0 + i;
    float acc[8];
    {
      const s16x8 v = *(const s16x8*)(h + tix(row, c0));
#pragma unroll
      for (int j = 0; j < 8; j++) acc[j] = b2f((u16)v[j]);
    }
    const int e0 = s_off[i], e1 = s_off[i + 1];
    for (int e = e0; e < e1; e++) {
      const int src = s_src[e];
      const s16x8 v = *(const s16x8*)(h + tix(src, c0));
#pragma unroll
      for (int j = 0; j < 8; j++) acc[j] += b2f((u16)v[j]);
    }
    s16x8 o;
#pragma unroll
    for (int j = 0; j < 8; j++) o[j] = (short)f2b(acc[j]);
    *(s16x8*)(z + tix(row, c0)) = o;
  }
}

// ---------------------------------------------------------------------------
// MFMA bf16 GEMM, 64x64 tile / BK=64 / 4 waves (2x2, wave-tile 32x32).
// EXACT round-5 body. Grid dim3(NCT, 1024), col-tile fastest (L2 reuse).
// ---------------------------------------------------------------------------
template <int NC, int K, int RELU, int RES, int STATS, int ASPLIT, int CMODE>
__global__ __launch_bounds__(256) void gemm_mfma(
    const u16* A, const u16* A2,
    const u16* __restrict__ W, const u16* __restrict__ bias,
    const u16* res, u16* C0, u16* C1, u16* C2,
    float* __restrict__ gsum, float* __restrict__ gsq) {
  __shared__ u16 As[2][64 * 64] __attribute__((aligned(16)));   // 8 KB each
  __shared__ u16 Bs[2][64 * 64] __attribute__((aligned(16)));

  const int t = threadIdx.x;
  const int wave = t >> 6, lane = t & 63;
  const int wr = wave >> 1, wc = wave & 1;
  const int quad = lane >> 4, ln15 = lane & 15;
  const int row0 = blockIdx.y * 64, col0 = blockIdx.x * 64;

  f32x4 acc[2][2];
#pragma unroll
  for (int i = 0; i < 2; i++)
#pragma unroll
    for (int j = 0; j < 2; j++) acc[i][j] = (f32x4){0.f, 0.f, 0.f, 0.f};

  auto stage = [&](int b, int kt) {
    const u16* Ab;
    int ksl;
    if (ASPLIT) {
      if (kt < 256) { Ab = A; ksl = kt >> 6; } else { Ab = A2; ksl = (kt - 256) >> 6; }
    } else {
      Ab = A; ksl = kt >> 6;
    }
    const u16* abase = Ab + ((size_t)(row0 >> 7) << 15) + (ksl << 13) +
                       ((row0 & 64) << 6);
#pragma unroll
    for (int i = 0; i < 2; i++) {
      const int fid = t + i * 256;            // 0..511
      glds16(abase + fid * 8, &As[b][fid * 8]);
      const int row = fid >> 3;               // 0..63 (C col)
      const int segp = (fid & 7) ^ (row & 7);
      glds16(W + (size_t)(col0 + row) * K + kt + segp * 8, &Bs[b][fid * 8]);
    }
  };

  stage(0, 0);
  for (int kt = 0; kt < K; kt += 64) {
    const int cur = (kt >> 6) & 1;
    if (kt + 64 < K) {
      stage(cur ^ 1, kt + 64);
      asm volatile("s_waitcnt vmcnt(4)" ::: "memory");
    } else {
      asm volatile("s_waitcnt vmcnt(0)" ::: "memory");
    }
    __builtin_amdgcn_s_barrier();
#pragma unroll
    for (int ks = 0; ks < 64; ks += 32) {
      s16x8 af[2], bf[2];
#pragma unroll
      for (int i = 0; i < 2; i++) {
        const int ra = wr * 32 + i * 16 + ln15;
        af[i] = *(const s16x8*)(
            &As[cur][ra * 64 + ((((ks >> 3) + quad) ^ (ra & 7)) * 8)]);
      }
#pragma unroll
      for (int j = 0; j < 2; j++) {
        const int rb = wc * 32 + j * 16 + ln15;
        bf[j] = *(const s16x8*)(
            &Bs[cur][rb * 64 + ((((ks >> 3) + quad) ^ (rb & 7)) * 8)]);
      }
#pragma unroll
      for (int i = 0; i < 2; i++)
#pragma unroll
        for (int j = 0; j < 2; j++)
          acc[i][j] = __builtin_amdgcn_mfma_f32_16x16x32_bf16(af[i], bf[j], acc[i][j], 0, 0, 0);
    }
    __builtin_amdgcn_s_barrier();
  }

  // ---- epilogue (tiled C / res) ----
  const int cbase = col0 + wc * 32;
  u16* Cb;
  int coff;
  if (CMODE) {
    const int chunk = col0 >> 8;
    Cb = (chunk == 0) ? C0 : ((chunk == 1) ? C1 : C2);
    coff = (col0 & 255) + wc * 32;
  } else {
    Cb = C0; coff = cbase;
  }

  float bs[2];
#pragma unroll
  for (int j = 0; j < 2; j++) bs[j] = b2f(bias[cbase + j * 16 + ln15]);

  float ssum[2] = {}, ssq[2] = {};
#pragma unroll
  for (int i = 0; i < 2; i++) {
    const int rbase = row0 + wr * 32 + i * 16 + quad * 4;
#pragma unroll
    for (int reg = 0; reg < 4; reg++) {
      const int row = rbase + reg;
#pragma unroll
      for (int j = 0; j < 2; j++) {
        float val = acc[i][j][reg] + bs[j];
        if (RELU) val = fmaxf(val, 0.f);
        if (RES) val += b2f(res[tix(row, cbase + j * 16 + ln15)]);
        Cb[tix(row, coff + j * 16 + ln15)] = f2b(val);
        if (STATS) { ssum[j] += val; ssq[j] += val * val; }
      }
    }
  }

  if (STATS) {
#pragma unroll
    for (int j = 0; j < 2; j++) {
      float s = ssum[j];
      s += __shfl_xor(s, 16);
      s += __shfl_xor(s, 32);
      float q = ssq[j];
      q += __shfl_xor(q, 16);
      q += __shfl_xor(q, 32);
      if (lane < 16) {
        atomicAdd(&gsum[cbase + j * 16 + lane], s);
        atomicAdd(&gsq[cbase + j * 16 + lane], q);
      }
    }
  }
}

// ---------------------------------------------------------------------------
// QKV GEMM (r12, kept): one block computes q, k AND v 64-col tiles; A staged
// once. Grid dim3(4, 1024). LDS As 16K + Bs 48K = 64 KB -> 2 blocks/CU.
// ---------------------------------------------------------------------------
__global__ __launch_bounds__(256) void qkv_mfma(
    const u16* A, const u16* __restrict__ W, const u16* __restrict__ bias,
    u16* Cq, u16* Ck, u16* Cv) {
  __shared__ u16 As[2][64 * 64] __attribute__((aligned(16)));      // 16 KB
  __shared__ u16 Bs[2][3 * 64 * 64] __attribute__((aligned(16)));  // 48 KB

  const int t = threadIdx.x;
  const int wave = t >> 6, lane = t & 63;
  const int wr = wave >> 1, wc = wave & 1;
  const int quad = lane >> 4, ln15 = lane & 15;
  const int row0 = blockIdx.y * 64, col0 = blockIdx.x * 64;

  f32x4 acc[3][2][2];
#pragma unroll
  for (int o = 0; o < 3; o++)
#pragma unroll
    for (int i = 0; i < 2; i++)
#pragma unroll
      for (int j = 0; j < 2; j++) acc[o][i][j] = (f32x4){0.f, 0.f, 0.f, 0.f};

  auto stage = [&](int b, int kt) {
    const u16* abase = A + ((size_t)(row0 >> 7) << 15) + ((kt >> 6) << 13) +
                       ((row0 & 64) << 6);
#pragma unroll
    for (int i = 0; i < 2; i++) {
      const int fid = t + i * 256;            // 0..511
      glds16(abase + fid * 8, &As[b][fid * 8]);
    }
#pragma unroll
    for (int o = 0; o < 3; o++)
#pragma unroll
      for (int i = 0; i < 2; i++) {
        const int fid = t + i * 256;
        const int row = fid >> 3;             // 0..63 (output col)
        const int segp = (fid & 7) ^ (row & 7);
        glds16(W + (size_t)(o * 256 + col0 + row) * 256 + kt + segp * 8,
               &Bs[b][o * 4096 + fid * 8]);
      }
  };

  stage(0, 0);
  for (int kt = 0; kt < 256; kt += 64) {
    const int cur = (kt >> 6) & 1;
    if (kt + 64 < 256) {
      stage(cur ^ 1, kt + 64);
      asm volatile("s_waitcnt vmcnt(8)" ::: "memory");
    } else {
      asm volatile("s_waitcnt vmcnt(0)" ::: "memory");
    }
    __builtin_amdgcn_s_barrier();
#pragma unroll
    for (int ks = 0; ks < 64; ks += 32) {
      s16x8 af[2];
#pragma unroll
      for (int i = 0; i < 2; i++) {
        const int ra = wr * 32 + i * 16 + ln15;
        af[i] = *(const s16x8*)(
            &As[cur][ra * 64 + ((((ks >> 3) + quad) ^ (ra & 7)) * 8)]);
      }
#pragma unroll
      for (int o = 0; o < 3; o++) {
        s16x8 bf[2];
#pragma unroll
        for (int j = 0; j < 2; j++) {
          const int rb = wc * 32 + j * 16 + ln15;
          bf[j] = *(const s16x8*)(
              &Bs[cur][o * 4096 + rb * 64 + ((((ks >> 3) + quad) ^ (rb & 7)) * 8)]);
        }
#pragma unroll
        for (int i = 0; i < 2; i++)
#pragma unroll
          for (int j = 0; j < 2; j++)
            acc[o][i][j] = __builtin_amdgcn_mfma_f32_16x16x32_bf16(af[i], bf[j], acc[o][i][j], 0, 0, 0);
      }
    }
    __builtin_amdgcn_s_barrier();
  }

  const int cbase = col0 + wc * 32;
#pragma unroll
  for (int o = 0; o < 3; o++) {
    u16* Co = (o == 0) ? Cq : ((o == 1) ? Ck : Cv);
    float bs[2];
#pragma unroll
    for (int j = 0; j < 2; j++) bs[j] = b2f(bias[o * 256 + cbase + j * 16 + ln15]);
#pragma unroll
    for (int i = 0; i < 2; i++) {
      const int rbase = row0 + wr * 32 + i * 16 + quad * 4;
#pragma unroll
      for (int reg = 0; reg < 4; reg++) {
        const int row = rbase + reg;
#pragma unroll
        for (int j = 0; j < 2; j++)
          Co[tix(row, cbase + j * 16 + ln15)] = f2b(acc[o][i][j][reg] + bs[j]);
      }
    }
  }
}

// ---------------------------------------------------------------------------
// Fused 2-layer MLP (r14 = r12 body + bn-fold COMBINE):
//   COMBINE=0: x = A via glds16 (r8-verified path)
//   COMBINE=1: x = bn_l(A)+bn_a(Ara); BN coefficients computed IN-KERNEL from
//              raw stats sums (bn_finalize folded; identical fp32 math).
//   C = x + relu(x@W1^T + b1)@W2^T + b2 (+res), + stats.
// r9: weights MUST stage via wave-linear glds16. r11: deeper W pipelining
// NEUTRAL. r13: gather fold REGRESSED (latency phase needs occupancy).
// LDS 80 KB -> 2 blocks/CU.
// ---------------------------------------------------------------------------
template <int CHUNKS, int RES_LDS, int COMBINE>
__global__ __launch_bounds__(256, 2) void fused_mlp(
    const u16* A, const u16* Ara,
    const u16* __restrict__ W1, const u16* __restrict__ b1,
    const u16* __restrict__ W2, const u16* __restrict__ b2,
    const u16* resg, u16* C, const float* __restrict__ st,
    const float* __restrict__ bn0g, const float* __restrict__ bn0b,
    const float* __restrict__ bn1g, const float* __restrict__ bn1b,
    float* __restrict__ gsum, float* __restrict__ gsq) {
  __shared__ u16 xs[4 * 64 * 64] __attribute__((aligned(16)));    // 32 KB
  __shared__ u16 tc[64 * 128] __attribute__((aligned(16)));       // 16 KB
  __shared__ u16 Wst[2][128 * 64] __attribute__((aligned(16)));   // 32 KB

  const int t = threadIdx.x;
  const int wave = t >> 6, lane = t & 63;
  const int wr = wave >> 1, wc = wave & 1;
  const int quad = lane >> 4, ln15 = lane & 15;
  const int row0 = blockIdx.x * 64;
  const int K2 = CHUNKS * 128;   // W2 row stride

  // ---- stage x rows row0..+63, all 256 cols ----
  if (COMBINE) {
    // bn_finalize folded: compute al|bl|aa|ba from raw sums -> cf (tc region)
    float* cf = (float*)tc;
    {
      const float ml = st[t] * (1.f / R_);
      const float vl = fmaxf(st[256 + t] * (1.f / R_) - ml * ml, 0.f);
      const float al = bn0g[t] * rsqrtf(vl + 1e-5f);
      cf[t] = al;
      cf[256 + t] = bn0b[t] - ml * al;
      const float ma = st[512 + t] * (1.f / R_);
      const float va = fmaxf(st[768 + t] * (1.f / R_) - ma * ma, 0.f);
      const float aa = bn1g[t] * rsqrtf(va + 1e-5f);
      cf[512 + t] = aa;
      cf[768 + t] = bn1b[t] - ma * aa;
    }
    __syncthreads();
    const size_t tbase = ((size_t)(row0 >> 7) << 15) + ((row0 & 64) << 6);
#pragma unroll
    for (int i = 0; i < 8; i++) {
      const int gid = t + i * 256;        // 0..2047 16B-chunks
      const int kstep = gid >> 9;
      const int fid = gid & 511;
      const size_t addr = tbase + kstep * 8192 + fid * 8;
      const s16x8 rl = *(const s16x8*)(A + addr);
      const s16x8 ra = *(const s16x8*)(Ara + addr);
      const int seg = (fid & 7) ^ ((fid >> 3) & 7);
      const int col = kstep * 64 + seg * 8;
      const float4 al0 = *(const float4*)(cf + col);
      const float4 al1 = *(const float4*)(cf + col + 4);
      const float4 bl0 = *(const float4*)(cf + 256 + col);
      const float4 bl1 = *(const float4*)(cf + 256 + col + 4);
      const float4 aa0 = *(const float4*)(cf + 512 + col);
      const float4 aa1 = *(const float4*)(cf + 512 + col + 4);
      const float4 ba0 = *(const float4*)(cf + 768 + col);
      const float4 ba1 = *(const float4*)(cf + 768 + col + 4);
      const float al[8] = {al0.x, al0.y, al0.z, al0.w, al1.x, al1.y, al1.z, al1.w};
      const float bl[8] = {bl0.x, bl0.y, bl0.z, bl0.w, bl1.x, bl1.y, bl1.z, bl1.w};
      const float aa[8] = {aa0.x, aa0.y, aa0.z, aa0.w, aa1.x, aa1.y, aa1.z, aa1.w};
      const float ba[8] = {ba0.x, ba0.y, ba0.z, ba0.w, ba1.x, ba1.y, ba1.z, ba1.w};
      s16x8 o;
#pragma unroll
      for (int j = 0; j < 8; j++)
        o[j] = (short)f2b(al[j] * b2f((u16)rl[j]) + bl[j] +
                          aa[j] * b2f((u16)ra[j]) + ba[j]);
      *(s16x8*)(xs + gid * 8) = o;
    }
    __syncthreads();   // xs ready; tc coeffs dead, reusable
  } else {
    const u16* abase = A + ((size_t)(row0 >> 7) << 15) + ((row0 & 64) << 6);
#pragma unroll
    for (int i = 0; i < 8; i++) {
      const int gid = t + i * 256;        // 0..2047 16B-loads
      const int kstep = gid >> 9;
      const int fid = gid & 511;
      glds16(abase + kstep * 8192 + fid * 8, xs + gid * 8);
    }
  }

  f32x4 acc2[2][8];
#pragma unroll
  for (int i = 0; i < 2; i++)
#pragma unroll
    for (int j = 0; j < 8; j++) acc2[i][j] = (f32x4){0.f, 0.f, 0.f, 0.f};

  // t-chunk LDS addressing: conflict-free column-slice b128 reads
  auto tca = [&](int row, int col) {
    const int s0 = col >> 3;
    return row * 128 + (((s0 & 8) | ((s0 ^ row) & 7)) << 3) + (col & 7);
  };

  for (int c = 0; c < CHUNKS; c++) {
    // ================= GEMM1: tchunk = relu(x @ W1[c*128..+128]^T) =========
    f32x4 acc1[2][4];
#pragma unroll
    for (int i = 0; i < 2; i++)
#pragma unroll
      for (int j = 0; j < 4; j++) acc1[i][j] = (f32x4){0.f, 0.f, 0.f, 0.f};

    auto stage1 = [&](int b, int kt) {
#pragma unroll
      for (int i = 0; i < 4; i++) {
        const int fid = t + i * 256;      // 0..1023
        const int row = fid >> 3;         // 0..127
        const int segp = (fid & 7) ^ (row & 7);
        glds16(W1 + (size_t)(c * 128 + row) * 256 + kt + segp * 8,
               &Wst[b][fid * 8]);
      }
    };

    stage1(0, 0);
    for (int kt = 0; kt < 256; kt += 64) {
      const int cur = (kt >> 6) & 1;
      if (kt + 64 < 256) {
        stage1(cur ^ 1, kt + 64);
        asm volatile("s_waitcnt vmcnt(4)" ::: "memory");
      } else {
        asm volatile("s_waitcnt vmcnt(0)" ::: "memory");
      }
      __builtin_amdgcn_s_barrier();
#pragma unroll
      for (int ks = 0; ks < 64; ks += 32) {
        s16x8 af[2], bf[4];
#pragma unroll
        for (int i = 0; i < 2; i++) {
          const int ra = wr * 32 + i * 16 + ln15;
          af[i] = *(const s16x8*)(
              &xs[(kt >> 6) * 4096 + ra * 64 +
                  ((((ks >> 3) + quad) ^ (ra & 7)) * 8)]);
        }
#pragma unroll
        for (int j = 0; j < 4; j++) {
          const int rb = wc * 64 + j * 16 + ln15;
          bf[j] = *(const s16x8*)(
              &Wst[cur][rb * 64 + ((((ks >> 3) + quad) ^ (rb & 7)) * 8)]);
        }
#pragma unroll
        for (int i = 0; i < 2; i++)
#pragma unroll
          for (int j = 0; j < 4; j++)
            acc1[i][j] = __builtin_amdgcn_mfma_f32_16x16x32_bf16(af[i], bf[j], acc1[i][j], 0, 0, 0);
      }
      __builtin_amdgcn_s_barrier();
    }

    // relu + bias -> tc (bf16)
    {
      float b1s[4];
#pragma unroll
      for (int j = 0; j < 4; j++)
        b1s[j] = b2f(b1[c * 128 + wc * 64 + j * 16 + ln15]);
#pragma unroll
      for (int i = 0; i < 2; i++)
#pragma unroll
        for (int reg = 0; reg < 4; reg++) {
          const int rowl = wr * 32 + i * 16 + quad * 4 + reg;
#pragma unroll
          for (int j = 0; j < 4; j++) {
            const int coll = wc * 64 + j * 16 + ln15;
            tc[tca(rowl, coll)] = f2b(fmaxf(acc1[i][j][reg] + b1s[j], 0.f));
          }
        }
    }
    __syncthreads();   // tc ready; Wst free

    // ================= GEMM2: acc2 += tchunk @ W2[:, c*128..+128]^T ========
    for (int ks2 = 0; ks2 < 2; ks2++) {
#pragma unroll
      for (int i = 0; i < 8; i++) {
        const int fid = t + i * 256;      // 0..2047
        const int row = fid >> 3;         // 0..255
        const int segp = (fid & 7) ^ (row & 7);
        glds16(W2 + (size_t)row * K2 + c * 128 + ks2 * 64 + segp * 8,
               &Wst[0][fid * 8]);
      }
      asm volatile("s_waitcnt vmcnt(0)" ::: "memory");
      __builtin_amdgcn_s_barrier();
#pragma unroll
      for (int ksl = 0; ksl < 64; ksl += 32) {
        s16x8 af[2], bf[8];
#pragma unroll
        for (int i = 0; i < 2; i++) {
          const int ra = wr * 32 + i * 16 + ln15;
          af[i] = *(const s16x8*)(&tc[tca(ra, ks2 * 64 + ksl + quad * 8)]);
        }
#pragma unroll
        for (int j = 0; j < 8; j++) {
          const int rb = wc * 128 + j * 16 + ln15;
          bf[j] = *(const s16x8*)(
              &Wst[0][rb * 64 + ((((ksl >> 3) + quad) ^ (rb & 7)) * 8)]);
        }
#pragma unroll
        for (int i = 0; i < 2; i++)
#pragma unroll
          for (int j = 0; j < 8; j++)
            acc2[i][j] = __builtin_amdgcn_mfma_f32_16x16x32_bf16(af[i], bf[j], acc2[i][j], 0, 0, 0);
      }
      __builtin_amdgcn_s_barrier();
    }
  }

  // ---- epilogue: y = acc2 + b2 + res -> C (tiled) + stats ----
  float bs2[8];
#pragma unroll
  for (int j = 0; j < 8; j++)
    bs2[j] = b2f(b2[wc * 128 + j * 16 + ln15]);

  float ssum[8] = {}, ssq[8] = {};
#pragma unroll
  for (int i = 0; i < 2; i++) {
#pragma unroll
    for (int reg = 0; reg < 4; reg++) {
      const int rowl = wr * 32 + i * 16 + quad * 4 + reg;
      const int row = row0 + rowl;
#pragma unroll
      for (int j = 0; j < 8; j++) {
        const int col = wc * 128 + j * 16 + ln15;
        float val = acc2[i][j][reg] + bs2[j];
        if (RES_LDS) {
          val += b2f(xs[(col >> 6) * 4096 + rowl * 64 +
                        ((((col >> 3) & 7) ^ (rowl & 7)) << 3) + (col & 7)]);
        } else {
          val += b2f(resg[tix(row, col)]);
        }
        C[tix(row, col)] = f2b(val);
        ssum[j] += val; ssq[j] += val * val;
      }
    }
  }

#pragma unroll
  for (int j = 0; j < 8; j++) {
    float s = ssum[j];
    s += __shfl_xor(s, 16);
    s += __shfl_xor(s, 32);
    float q = ssq[j];
    q += __shfl_xor(q, 16);
    q += __shfl_xor(q, 32);
    if (lane < 16) {
      atomicAdd(&gsum[wc * 128 + j * 16 + lane], s);
      atomicAdd(&gsq[wc * 128 + j * 16 + lane], q);
    }
  }
}

// ---------------------------------------------------------------------------
// MFMA attention: one block per (graph, head), 4 waves; q/k/v/o tiled (tix).
// ---------------------------------------------------------------------------
__global__ __launch_bounds__(256) void attn_mfma(
    const u16* q, const u16* __restrict__ k,
    const u16* __restrict__ v, u16* o) {
  __shared__ u16 lds[21760] __attribute__((aligned(16)));
  u16* Vt = lds;                   // [32][136]  V transposed (d-major)
  u16* Qs = lds + 4352;            // [128][40]  scaled Q
  u16* Ks = lds + 4352 + 5120;     // [128][40]
  u16* P  = lds + 4352;            // [128][136] aliases Qs/Ks after barrier

  const int g = blockIdx.x >> 3;
  const int hd = blockIdx.x & 7;
  const int t = threadIdx.x;
  const int wave = t >> 6, lane = t & 63;
  const int quad = lane >> 4, ln15 = lane & 15;
  const int strip = wave * 32;
  const float scale = 0.1767766952966369f;  // 1/sqrt(32)

  // ---- stage Q (pre-scaled), K, V^T ----
#pragma unroll
  for (int i = 0; i < 4; i++) {
    const int fid = t + i * 256;   // 0..1023
    const int row = fid >> 3;
    const int seg = fid & 7;       // 4 u16 each
    const int gidx = tix(g * N_ + row, hd * HD_ + seg * 4);
    const ushort4 qv = *(const ushort4*)(q + gidx);
    const ushort4 kv = *(const ushort4*)(k + gidx);
    const ushort4 vv = *(const ushort4*)(v + gidx);
    ushort4 qs;
    qs.x = f2b(b2f(qv.x) * scale); qs.y = f2b(b2f(qv.y) * scale);
    qs.z = f2b(b2f(qv.z) * scale); qs.w = f2b(b2f(qv.w) * scale);
    *(ushort4*)(Qs + row * 40 + seg * 4) = qs;
    *(ushort4*)(Ks + row * 40 + seg * 4) = kv;
    Vt[(seg * 4 + 0) * 136 + row] = vv.x;
    Vt[(seg * 4 + 1) * 136 + row] = vv.y;
    Vt[(seg * 4 + 2) * 136 + row] = vv.z;
    Vt[(seg * 4 + 3) * 136 + row] = vv.w;
  }
  __syncthreads();

  // ---- S = Q K^T (strip x 128) ----
  s16x8 af[2], bf[8];
#pragma unroll
  for (int mi = 0; mi < 2; mi++)
    af[mi] = *(const s16x8*)(Qs + (strip + mi * 16 + ln15) * 40 + quad * 8);
#pragma unroll
  for (int nj = 0; nj < 8; nj++)
    bf[nj] = *(const s16x8*)(Ks + (nj * 16 + ln15) * 40 + quad * 8);

  f32x4 acc[2][8];
#pragma unroll
  for (int mi = 0; mi < 2; mi++)
#pragma unroll
    for (int nj = 0; nj < 8; nj++)
      acc[mi][nj] = __builtin_amdgcn_mfma_f32_16x16x32_bf16(
          af[mi], bf[nj], (f32x4){0.f, 0.f, 0.f, 0.f}, 0, 0, 0);

  __syncthreads();  // Q/K dead; region becomes P

  // ---- softmax per row, write P ----
#pragma unroll
  for (int mi = 0; mi < 2; mi++) {
#pragma unroll
    for (int reg = 0; reg < 4; reg++) {
      float mx = acc[mi][0][reg];
#pragma unroll
      for (int j = 1; j < 8; j++) mx = fmaxf(mx, acc[mi][j][reg]);
      mx = fmaxf(mx, __shfl_xor(mx, 1));
      mx = fmaxf(mx, __shfl_xor(mx, 2));
      mx = fmaxf(mx, __shfl_xor(mx, 4));
      mx = fmaxf(mx, __shfl_xor(mx, 8));
      float e[8], s = 0.f;
#pragma unroll
      for (int j = 0; j < 8; j++) { e[j] = __expf(acc[mi][j][reg] - mx); s += e[j]; }
      s += __shfl_xor(s, 1);
      s += __shfl_xor(s, 2);
      s += __shfl_xor(s, 4);
      s += __shfl_xor(s, 8);
      const float inv = 1.f / s;
      const int prow = strip + mi * 16 + quad * 4 + reg;
#pragma unroll
      for (int j = 0; j < 8; j++)
        P[prow * 136 + j * 16 + ln15] = f2b(e[j] * inv);
    }
  }
  __syncthreads();

  // ---- O = P V (strip x 32) ----
  f32x4 acc2[2][2];
#pragma unroll
  for (int mi = 0; mi < 2; mi++)
#pragma unroll
    for (int nj = 0; nj < 2; nj++) acc2[mi][nj] = (f32x4){0.f, 0.f, 0.f, 0.f};
#pragma unroll
  for (int kt = 0; kt < 4; kt++) {
    s16x8 paf[2], vbf[2];
#pragma unroll
    for (int mi = 0; mi < 2; mi++)
      paf[mi] = *(const s16x8*)(P + (strip + mi * 16 + ln15) * 136 + kt * 32 + quad * 8);
#pragma unroll
    for (int nj = 0; nj < 2; nj++)
      vbf[nj] = *(const s16x8*)(Vt + (nj * 16 + ln15) * 136 + kt * 32 + quad * 8);
#pragma unroll
    for (int mi = 0; mi < 2; mi++)
#pragma unroll
      for (int nj = 0; nj < 2; nj++)
        acc2[mi][nj] = __builtin_amdgcn_mfma_f32_16x16x32_bf16(
            paf[mi], vbf[nj], acc2[mi][nj], 0, 0, 0);
  }

#pragma unroll
  for (int mi = 0; mi < 2; mi++)
#pragma unroll
    for (int nj = 0; nj < 2; nj++)
#pragma unroll
      for (int reg = 0; reg < 4; reg++) {
        const int row = strip + mi * 16 + quad * 4 + reg;
        o[tix(g * N_ + row, hd * HD_ + nj * 16 + ln15)] =
            f2b(acc2[mi][nj][reg]);
      }
}

// out = bn_out(y) with bn_finalize folded: per-thread coefficient compute.
__global__ __launch_bounds__(256) void final_kernel(
    const u16* __restrict__ y, const float* __restrict__ st,
    const float* __restrict__ bg, const float* __restrict__ bb,
    float* __restrict__ out) {
  const int e = (blockIdx.x * 256 + threadIdx.x) * 4;
  const int col = e & 255;
  float y4[4];
  ld4b(y + tix(e >> 8, col), y4);
  const float4 s4 = *(const float4*)(st + 1024 + col);
  const float4 q4 = *(const float4*)(st + 1280 + col);
  const float4 g4 = *(const float4*)(bg + col);
  const float4 b4 = *(const float4*)(bb + col);
  const float ss[4] = {s4.x, s4.y, s4.z, s4.w};
  const float qq[4] = {q4.x, q4.y, q4.z, q4.w};
  const float gg[4] = {g4.x, g4.y, g4.z, g4.w};
  const float bv[4] = {b4.x, b4.y, b4.z, b4.w};
  float4 o;
  float* ov = (float*)&o;
#pragma unroll
  for (int j = 0; j < 4; j++) {
    const float mean = ss[j] * (1.f / R_);
    const float var = fmaxf(qq[j] * (1.f / R_) - mean * mean, 0.f);
    const float a = gg[j] * rsqrtf(var + 1e-5f);
    ov[j] = a * y4[j] + (bv[j] - mean * a);
  }
  *(float4*)(out + e) = o;
}

extern "C" void kernel_launch(void* const* d_in, const int* in_sizes, int n_in,
                              void* d_out, int out_size, void* d_ws, size_t ws_size,
                              hipStream_t stream) {
  const float* h = (const float*)d_in[0];
  const int* esrc = (const int*)d_in[1];
  const int* edst = (const int*)d_in[2];
  const float* bn_local_g = (const float*)d_in[11];
  const float* bn_local_b = (const float*)d_in[12];
  const float* bn_attn_g = (const float*)d_in[13];
  const float* bn_attn_b = (const float*)d_in[14];
  const float* bn_out_g = (const float*)d_in[15];
  const float* bn_out_b = (const float*)d_in[16];

  const size_t RH = (size_t)R_ * H_;
  float* stats = (float*)d_ws;                        // 1536 floats used
  u16* WB = (u16*)((char*)d_ws + 65536);              // packed bf16 weights ~1.3 MB
  u16* Hb = (u16*)((char*)d_ws + 65536 + 2097152);    // h in bf16 (tiled), 32 MB
  u16* S1 = Hb + RH;                                  // 32 MB
  u16* S2 = S1 + RH;                                  // 32 MB
  u16* OD = (u16*)d_out;                              // first 32 MB of d_out as bf16 scratch
  float* outf = (float*)d_out;                        // final fp32 out (64 MB)

  // cvt_h + cvt_w + zero_stats in one launch
  prep_kernel<<<16384 + 643 + 12, 256, 0, stream>>>(
      h, Hb,
      (const float*)d_in[3], (const float*)d_in[4], (const float*)d_in[5],
      (const float*)d_in[6], (const float*)d_in[7], (const float*)d_in[8],
      (const float*)d_in[9], (const float*)d_in[10], (const float*)d_in[17],
      (const float*)d_in[18], (const float*)d_in[19], (const float*)d_in[20],
      WB, stats);

  // qkv: A staged once per block for all of q,k,v -> q=S1, k=S2, v=OD
  qkv_mfma<<<dim3(4, 1024), 256, 0, stream>>>(
      Hb, WB + OFF_AIW, WB + OFF_AIB, S1, S2, OD);
  // o = softmax(q k^T / sqrt(32)) v, in-place over q (S1)
  attn_mfma<<<B_ * NH_, 256, 0, stream>>>(S1, S2, OD, S1);
  // r_attn = h + o@Wo^T -> S2, + stats_attn
  gemm_mfma<256, 256, 0, 1, 1, 0, 0><<<dim3(4, 1024), 256, 0, stream>>>(
      S1, nullptr, WB + OFF_AOW, WB + OFF_AOB, Hb, S2, nullptr, nullptr,
      stats + 512, stats + 768);
  // z = h + segment_sum -> OD (standalone high-occupancy kernel)
  agg_kernel<<<dim3(B_, 4), 256, 0, stream>>>(Hb, esrc, edst, OD);
  // r_local = h + relu(z@GW1+b1)@GW2+b2 -> OD in place, + stats_local
  fused_mlp<2, 0, 0><<<1024, 256, 0, stream>>>(
      OD, nullptr,
      WB + OFF_GW1, WB + OFF_GB1, WB + OFF_GW2, WB + OFF_GB2,
      Hb, OD, nullptr, nullptr, nullptr, nullptr, nullptr,
      stats + 0, stats + 256);
  // y = x + relu(x@F1+b1)@F2+b2 -> S1; x = bn_l(OD)+bn_a(S2) with BN
  // coefficients computed in-kernel (combine + bn_finalize folds), + stats_out
  fused_mlp<4, 1, 1><<<1024, 256, 0, stream>>>(
      OD, S2,
      WB + OFF_F1W, WB + OFF_F1B, WB + OFF_F2W, WB + OFF_F2B,
      nullptr, S1, stats, bn_local_g, bn_local_b, bn_attn_g, bn_attn_b,
      stats + 1024, stats + 1280);
  // out = bn_out(y S1) -> fp32 d_out (bn_finalize folded)
  final_kernel<<<(int)(RH / 4 / 256), 256, 0, stream>>>(
      S1, stats, bn_out_g, bn_out_b, outf);
}

// Round 15
// 522.330 us; speedup vs baseline: 1.0465x; 1.0195x over previous
//
#include <hip/hip_runtime.h>
#include <hip/hip_bf16.h>

#define B_   512
#define N_   128
#define H_   256
#define NH_  8
#define HD_  32
#define DEG_ 8
#define R_   (B_ * N_)          // 65536 rows
#define E_   (B_ * N_ * DEG_)   // 524288 edges
#define EPG_ (N_ * DEG_)        // 1024 edges per graph

typedef unsigned short u16;
typedef unsigned int u32;

typedef __attribute__((ext_vector_type(8))) short s16x8;   // 8 bf16 = 4 VGPRs
typedef __attribute__((ext_vector_type(4))) float f32x4;   // MFMA acc

__device__ __forceinline__ float b2f(u16 u) {
  union { u32 i; float f; } v;
  v.i = ((u32)u) << 16;
  return v.f;
}
__device__ __forceinline__ u16 f2b(float f) {
  union { float f; u32 u; } v;
  v.f = f;
  u32 r = (v.u + 0x7fffu + ((v.u >> 16) & 1u)) >> 16;  // RNE
  return (u16)r;
}
__device__ __forceinline__ void ld4b(const u16* p, float* o) {
  ushort4 v = *(const ushort4*)p;
  o[0] = b2f(v.x); o[1] = b2f(v.y); o[2] = b2f(v.z); o[3] = b2f(v.w);
}

// ---------------------------------------------------------------------------
// Tiled-swizzled layout for ALL 256-col bf16 intermediates:
//   [rowblk=row>>7][kstep=col>>6][row&127][seg: ((col>>3)&7)^(row&7)][col&7]
// ---------------------------------------------------------------------------
__device__ __forceinline__ int tix(int row, int col) {
  return ((row >> 7) << 15) + (((col >> 6) & 3) << 13) + ((row & 127) << 6) +
         (((((col >> 3) & 7) ^ (row & 7))) << 3) + (col & 7);
}

__device__ __forceinline__ void glds16(const u16* g, u16* l) {
  __builtin_amdgcn_global_load_lds(
      (const __attribute__((address_space(1))) void*)g,
      (__attribute__((address_space(3))) void*)l, 16, 0, 0);
}

// stats layout (floats, at d_ws + 0):
//   0..255 sum_local | 256..511 sq_local | 512..767 sum_attn | 768..1023 sq_attn
//   1024..1279 sum_out | 1280..1535 sq_out

// packed bf16 weight area offsets (u16 elements)
#define OFF_GW1 0
#define OFF_GB1 65536
#define OFF_GW2 65792
#define OFF_GB2 131328
#define OFF_AIW 131584
#define OFF_AIB 328192
#define OFF_AOW 328960
#define OFF_AOB 394496
#define OFF_F1W 394752
#define OFF_F1B 525824
#define OFF_F2W 526336
#define OFF_F2B 657408
#define W_TOTAL 657664

// ---------------------------------------------------------------------------
// prep: cvt_h (blocks 0..16383) + cvt_w (16384..17026) + zero stats (17027..)
// ---------------------------------------------------------------------------
__global__ __launch_bounds__(256) void prep_kernel(
    const float* __restrict__ hsrc, u16* __restrict__ hdst,
    const float* s0, const float* s1, const float* s2, const float* s3,
    const float* s4, const float* s5, const float* s6, const float* s7,
    const float* s8, const float* s9, const float* s10, const float* s11,
    u16* __restrict__ wdst, float* __restrict__ stats) {
  const int b = blockIdx.x, t = threadIdx.x;
  if (b < 16384) {
    const int e = (b * 256 + t) * 4;
    const float4 v = *(const float4*)(hsrc + e);
    ushort4 o;
    o.x = f2b(v.x); o.y = f2b(v.y); o.z = f2b(v.z); o.w = f2b(v.w);
    *(ushort4*)(hdst + tix(e >> 8, e & 255)) = o;
  } else if (b < 16384 + 643) {
    const int sizes[12] = {65536, 256, 65536, 256, 196608, 768,
                           65536, 256, 131072, 512, 131072, 256};
    const float* srcs[12] = {s0, s1, s2, s3, s4, s5, s6, s7, s8, s9, s10, s11};
    int gid = ((b - 16384) * 256 + t) * 4;
    if (gid >= W_TOTAL) return;
    int seg = 0, off = gid;
    while (off >= sizes[seg]) { off -= sizes[seg]; seg++; }
    const float4 v = *(const float4*)(srcs[seg] + off);
    ushort4 o;
    o.x = f2b(v.x); o.y = f2b(v.y); o.z = f2b(v.z); o.w = f2b(v.w);
    *(ushort4*)(wdst + gid) = o;
  } else {
    stats[(b - (16384 + 643)) * 256 + t] = 0.f;
  }
}

// ---------------------------------------------------------------------------
// QKV GEMM (r12, kept): one block computes q, k AND v 64-col tiles; A staged
// once. Grid dim3(4, 1024). LDS As 16K + Bs 48K = 64 KB -> 2 blocks/CU.
// ---------------------------------------------------------------------------
__global__ __launch_bounds__(256) void qkv_mfma(
    const u16* A, const u16* __restrict__ W, const u16* __restrict__ bias,
    u16* Cq, u16* Ck, u16* Cv) {
  __shared__ u16 As[2][64 * 64] __attribute__((aligned(16)));      // 16 KB
  __shared__ u16 Bs[2][3 * 64 * 64] __attribute__((aligned(16)));  // 48 KB

  const int t = threadIdx.x;
  const int wave = t >> 6, lane = t & 63;
  const int wr = wave >> 1, wc = wave & 1;
  const int quad = lane >> 4, ln15 = lane & 15;
  const int row0 = blockIdx.y * 64, col0 = blockIdx.x * 64;

  f32x4 acc[3][2][2];
#pragma unroll
  for (int o = 0; o < 3; o++)
#pragma unroll
    for (int i = 0; i < 2; i++)
#pragma unroll
      for (int j = 0; j < 2; j++) acc[o][i][j] = (f32x4){0.f, 0.f, 0.f, 0.f};

  auto stage = [&](int b, int kt) {
    const u16* abase = A + ((size_t)(row0 >> 7) << 15) + ((kt >> 6) << 13) +
                       ((row0 & 64) << 6);
#pragma unroll
    for (int i = 0; i < 2; i++) {
      const int fid = t + i * 256;            // 0..511
      glds16(abase + fid * 8, &As[b][fid * 8]);
    }
#pragma unroll
    for (int o = 0; o < 3; o++)
#pragma unroll
      for (int i = 0; i < 2; i++) {
        const int fid = t + i * 256;
        const int row = fid >> 3;             // 0..63 (output col)
        const int segp = (fid & 7) ^ (row & 7);
        glds16(W + (size_t)(o * 256 + col0 + row) * 256 + kt + segp * 8,
               &Bs[b][o * 4096 + fid * 8]);
      }
  };

  stage(0, 0);
  for (int kt = 0; kt < 256; kt += 64) {
    const int cur = (kt >> 6) & 1;
    if (kt + 64 < 256) {
      stage(cur ^ 1, kt + 64);
      asm volatile("s_waitcnt vmcnt(8)" ::: "memory");
    } else {
      asm volatile("s_waitcnt vmcnt(0)" ::: "memory");
    }
    __builtin_amdgcn_s_barrier();
#pragma unroll
    for (int ks = 0; ks < 64; ks += 32) {
      s16x8 af[2];
#pragma unroll
      for (int i = 0; i < 2; i++) {
        const int ra = wr * 32 + i * 16 + ln15;
        af[i] = *(const s16x8*)(
            &As[cur][ra * 64 + ((((ks >> 3) + quad) ^ (ra & 7)) * 8)]);
      }
#pragma unroll
      for (int o = 0; o < 3; o++) {
        s16x8 bf[2];
#pragma unroll
        for (int j = 0; j < 2; j++) {
          const int rb = wc * 32 + j * 16 + ln15;
          bf[j] = *(const s16x8*)(
              &Bs[cur][o * 4096 + rb * 64 + ((((ks >> 3) + quad) ^ (rb & 7)) * 8)]);
        }
#pragma unroll
        for (int i = 0; i < 2; i++)
#pragma unroll
          for (int j = 0; j < 2; j++)
            acc[o][i][j] = __builtin_amdgcn_mfma_f32_16x16x32_bf16(af[i], bf[j], acc[o][i][j], 0, 0, 0);
      }
    }
    __builtin_amdgcn_s_barrier();
  }

  const int cbase = col0 + wc * 32;
#pragma unroll
  for (int o = 0; o < 3; o++) {
    u16* Co = (o == 0) ? Cq : ((o == 1) ? Ck : Cv);
    float bs[2];
#pragma unroll
    for (int j = 0; j < 2; j++) bs[j] = b2f(bias[o * 256 + cbase + j * 16 + ln15]);
#pragma unroll
    for (int i = 0; i < 2; i++) {
      const int rbase = row0 + wr * 32 + i * 16 + quad * 4;
#pragma unroll
      for (int reg = 0; reg < 4; reg++) {
        const int row = rbase + reg;
#pragma unroll
        for (int j = 0; j < 2; j++)
          Co[tix(row, cbase + j * 16 + ln15)] = f2b(acc[o][i][j][reg] + bs[j]);
      }
    }
  }
}

// ---------------------------------------------------------------------------
// attn + agg horizontally fused (r15): blocks 0..4095 = attention (one per
// (graph, head)); blocks 4096..6143 = edge aggregation slices. The two are
// independent (attn needs qkv output; agg needs only Hb) and agg writes z
// to OD2 so it cannot race attn's read of v (OD). LDS union = attn's 42.5 KB
// (agg's 4.4 KB CSR overlays it) -> attn occupancy unchanged; agg's short
// blocks backfill attn's tail for ~free.
// ---------------------------------------------------------------------------
__global__ __launch_bounds__(256) void attn_agg(
    const u16* q, const u16* __restrict__ k,
    const u16* __restrict__ v, u16* o,
    const u16* __restrict__ h, const int* __restrict__ esrc,
    const int* __restrict__ edst, u16* __restrict__ z) {
  __shared__ u16 lds[21760] __attribute__((aligned(16)));
  const int t = threadIdx.x;

  if (blockIdx.x < 4096) {
    // ================= attention (r14-exact body) =================
    u16* Vt = lds;                   // [32][136]
    u16* Qs = lds + 4352;            // [128][40]
    u16* Ks = lds + 4352 + 5120;     // [128][40]
    u16* P  = lds + 4352;            // [128][136] aliases Qs/Ks

    const int g = blockIdx.x >> 3;
    const int hd = blockIdx.x & 7;
    const int wave = t >> 6, lane = t & 63;
    const int quad = lane >> 4, ln15 = lane & 15;
    const int strip = wave * 32;
    const float scale = 0.1767766952966369f;  // 1/sqrt(32)

#pragma unroll
    for (int i = 0; i < 4; i++) {
      const int fid = t + i * 256;
      const int row = fid >> 3;
      const int seg = fid & 7;
      const int gidx = tix(g * N_ + row, hd * HD_ + seg * 4);
      const ushort4 qv = *(const ushort4*)(q + gidx);
      const ushort4 kv = *(const ushort4*)(k + gidx);
      const ushort4 vv = *(const ushort4*)(v + gidx);
      ushort4 qs;
      qs.x = f2b(b2f(qv.x) * scale); qs.y = f2b(b2f(qv.y) * scale);
      qs.z = f2b(b2f(qv.z) * scale); qs.w = f2b(b2f(qv.w) * scale);
      *(ushort4*)(Qs + row * 40 + seg * 4) = qs;
      *(ushort4*)(Ks + row * 40 + seg * 4) = kv;
      Vt[(seg * 4 + 0) * 136 + row] = vv.x;
      Vt[(seg * 4 + 1) * 136 + row] = vv.y;
      Vt[(seg * 4 + 2) * 136 + row] = vv.z;
      Vt[(seg * 4 + 3) * 136 + row] = vv.w;
    }
    __syncthreads();

    s16x8 af[2], bf[8];
#pragma unroll
    for (int mi = 0; mi < 2; mi++)
      af[mi] = *(const s16x8*)(Qs + (strip + mi * 16 + ln15) * 40 + quad * 8);
#pragma unroll
    for (int nj = 0; nj < 8; nj++)
      bf[nj] = *(const s16x8*)(Ks + (nj * 16 + ln15) * 40 + quad * 8);

    f32x4 acc[2][8];
#pragma unroll
    for (int mi = 0; mi < 2; mi++)
#pragma unroll
      for (int nj = 0; nj < 8; nj++)
        acc[mi][nj] = __builtin_amdgcn_mfma_f32_16x16x32_bf16(
            af[mi], bf[nj], (f32x4){0.f, 0.f, 0.f, 0.f}, 0, 0, 0);

    __syncthreads();  // Q/K dead; region becomes P

#pragma unroll
    for (int mi = 0; mi < 2; mi++) {
#pragma unroll
      for (int reg = 0; reg < 4; reg++) {
        float mx = acc[mi][0][reg];
#pragma unroll
        for (int j = 1; j < 8; j++) mx = fmaxf(mx, acc[mi][j][reg]);
        mx = fmaxf(mx, __shfl_xor(mx, 1));
        mx = fmaxf(mx, __shfl_xor(mx, 2));
        mx = fmaxf(mx, __shfl_xor(mx, 4));
        mx = fmaxf(mx, __shfl_xor(mx, 8));
        float e[8], s = 0.f;
#pragma unroll
        for (int j = 0; j < 8; j++) { e[j] = __expf(acc[mi][j][reg] - mx); s += e[j]; }
        s += __shfl_xor(s, 1);
        s += __shfl_xor(s, 2);
        s += __shfl_xor(s, 4);
        s += __shfl_xor(s, 8);
        const float inv = 1.f / s;
        const int prow = strip + mi * 16 + quad * 4 + reg;
#pragma unroll
        for (int j = 0; j < 8; j++)
          P[prow * 136 + j * 16 + ln15] = f2b(e[j] * inv);
      }
    }
    __syncthreads();

    f32x4 acc2[2][2];
#pragma unroll
    for (int mi = 0; mi < 2; mi++)
#pragma unroll
      for (int nj = 0; nj < 2; nj++) acc2[mi][nj] = (f32x4){0.f, 0.f, 0.f, 0.f};
#pragma unroll
    for (int kt = 0; kt < 4; kt++) {
      s16x8 paf[2], vbf[2];
#pragma unroll
      for (int mi = 0; mi < 2; mi++)
        paf[mi] = *(const s16x8*)(P + (strip + mi * 16 + ln15) * 136 + kt * 32 + quad * 8);
#pragma unroll
      for (int nj = 0; nj < 2; nj++)
        vbf[nj] = *(const s16x8*)(Vt + (nj * 16 + ln15) * 136 + kt * 32 + quad * 8);
#pragma unroll
      for (int mi = 0; mi < 2; mi++)
#pragma unroll
        for (int nj = 0; nj < 2; nj++)
          acc2[mi][nj] = __builtin_amdgcn_mfma_f32_16x16x32_bf16(
              paf[mi], vbf[nj], acc2[mi][nj], 0, 0, 0);
    }

#pragma unroll
    for (int mi = 0; mi < 2; mi++)
#pragma unroll
      for (int nj = 0; nj < 2; nj++)
#pragma unroll
        for (int reg = 0; reg < 4; reg++) {
          const int row = strip + mi * 16 + quad * 4 + reg;
          o[tix(g * N_ + row, hd * HD_ + nj * 16 + ln15)] =
              f2b(acc2[mi][nj][reg]);
        }
  } else {
    // ================= edge aggregation (r14-exact body) =================
    const int bid2 = blockIdx.x - 4096;
    const int g = bid2 & 511;               // graph (fastest, as dim3(512,4))
    const int r0 = (bid2 >> 9) * 32;        // 32-row slice
    int* s_src = (int*)lds;                 // 1024 ints
    int* s_cnt = (int*)(lds + 2048);        // 32
    int* s_off = (int*)(lds + 2112);        // 33
    int* s_pos = (int*)(lds + 2180);        // 32

    if (t < 32) s_cnt[t] = 0;
    __syncthreads();

    const int ebase = g * EPG_;
    int dl[4], sg[4];
#pragma unroll
    for (int i = 0; i < 4; i++) {
      const int e = ebase + t + i * 256;
      sg[i] = esrc[e];
      dl[i] = edst[e] - g * N_ - r0;
      if ((unsigned)dl[i] < 32u) atomicAdd(&s_cnt[dl[i]], 1);
    }
    __syncthreads();
    if (t == 0) {
      int acc = 0;
#pragma unroll
      for (int i = 0; i < 32; i++) { s_off[i] = acc; acc += s_cnt[i]; }
      s_off[32] = acc;
    }
    __syncthreads();
    if (t < 32) s_pos[t] = s_off[t];
    __syncthreads();
#pragma unroll
    for (int i = 0; i < 4; i++) {
      if ((unsigned)dl[i] < 32u) {
        const int slot = atomicAdd(&s_pos[dl[i]], 1);
        s_src[slot] = sg[i];
      }
    }
    __syncthreads();

    const int rg = t >> 5;
    const int c0 = (t & 31) * 8;
    for (int ib = 0; ib < 32; ib += 8) {
      const int i = ib + rg;
      const int row = g * N_ + r0 + i;
      float acc[8];
      {
        const s16x8 vv = *(const s16x8*)(h + tix(row, c0));
#pragma unroll
        for (int j = 0; j < 8; j++) acc[j] = b2f((u16)vv[j]);
      }
      const int e0 = s_off[i], e1 = s_off[i + 1];
      for (int e = e0; e < e1; e++) {
        const int src = s_src[e];
        const s16x8 vv = *(const s16x8*)(h + tix(src, c0));
#pragma unroll
        for (int j = 0; j < 8; j++) acc[j] += b2f((u16)vv[j]);
      }
      s16x8 ov;
#pragma unroll
      for (int j = 0; j < 8; j++) ov[j] = (short)f2b(acc[j]);
      *(s16x8*)(z + tix(row, c0)) = ov;
    }
  }
}

// ---------------------------------------------------------------------------
// GIN-MLP + AO-GEMM horizontally fused (r15): blocks 0..1023 = GIN fused MLP
// (long blocks first); 1024..5119 = AO output-projection GEMM. Independent
// after attn_agg. LDS union = GIN's 80 KB -> both at 2 blocks/CU; AO
// co-executes under GIN's schedule-bound bubbles instead of running serially.
// ---------------------------------------------------------------------------
__global__ __launch_bounds__(256, 2) void gin_ao(
    const u16* zA, const u16* __restrict__ gres,
    const u16* __restrict__ GW1, const u16* __restrict__ GB1,
    const u16* __restrict__ GW2, const u16* __restrict__ GB2,
    u16* Cgin, float* __restrict__ gsum_l, float* __restrict__ gsq_l,
    const u16* Aao, const u16* __restrict__ AOW, const u16* __restrict__ AOB,
    const u16* __restrict__ ares, u16* Cao,
    float* __restrict__ gsum_a, float* __restrict__ gsq_a) {
  __shared__ u16 shbuf[40960] __attribute__((aligned(16)));   // 80 KB union
  const int t = threadIdx.x;
  const int wave = t >> 6, lane = t & 63;
  const int wr = wave >> 1, wc = wave & 1;
  const int quad = lane >> 4, ln15 = lane & 15;

  if (blockIdx.x < 1024) {
    // ============ GIN fused MLP (r14 fused_mlp<2,0,0> body) ============
    u16* xs = shbuf;                    // 16384 u16 (32 KB)
    u16* tc = shbuf + 16384;            // 8192 u16 (16 KB)
    // Wst(b) = shbuf + 24576 + b*8192  (32 KB)
    const int row0 = blockIdx.x * 64;

    {
      const u16* abase = zA + ((size_t)(row0 >> 7) << 15) + ((row0 & 64) << 6);
#pragma unroll
      for (int i = 0; i < 8; i++) {
        const int gid = t + i * 256;
        const int kstep = gid >> 9;
        const int fid = gid & 511;
        glds16(abase + kstep * 8192 + fid * 8, xs + gid * 8);
      }
    }

    f32x4 acc2[2][8];
#pragma unroll
    for (int i = 0; i < 2; i++)
#pragma unroll
      for (int j = 0; j < 8; j++) acc2[i][j] = (f32x4){0.f, 0.f, 0.f, 0.f};

    auto tca = [&](int row, int col) {
      const int s0 = col >> 3;
      return row * 128 + (((s0 & 8) | ((s0 ^ row) & 7)) << 3) + (col & 7);
    };

    for (int c = 0; c < 2; c++) {
      f32x4 acc1[2][4];
#pragma unroll
      for (int i = 0; i < 2; i++)
#pragma unroll
        for (int j = 0; j < 4; j++) acc1[i][j] = (f32x4){0.f, 0.f, 0.f, 0.f};

      auto stage1 = [&](int b, int kt) {
#pragma unroll
        for (int i = 0; i < 4; i++) {
          const int fid = t + i * 256;
          const int row = fid >> 3;
          const int segp = (fid & 7) ^ (row & 7);
          glds16(GW1 + (size_t)(c * 128 + row) * 256 + kt + segp * 8,
                 shbuf + 24576 + b * 8192 + fid * 8);
        }
      };

      stage1(0, 0);
      for (int kt = 0; kt < 256; kt += 64) {
        const int cur = (kt >> 6) & 1;
        if (kt + 64 < 256) {
          stage1(cur ^ 1, kt + 64);
          asm volatile("s_waitcnt vmcnt(4)" ::: "memory");
        } else {
          asm volatile("s_waitcnt vmcnt(0)" ::: "memory");
        }
        __builtin_amdgcn_s_barrier();
#pragma unroll
        for (int ks = 0; ks < 64; ks += 32) {
          s16x8 af[2], bf[4];
#pragma unroll
          for (int i = 0; i < 2; i++) {
            const int ra = wr * 32 + i * 16 + ln15;
            af[i] = *(const s16x8*)(
                &xs[(kt >> 6) * 4096 + ra * 64 +
                    ((((ks >> 3) + quad) ^ (ra & 7)) * 8)]);
          }
#pragma unroll
          for (int j = 0; j < 4; j++) {
            const int rb = wc * 64 + j * 16 + ln15;
            bf[j] = *(const s16x8*)(
                shbuf + 24576 + cur * 8192 + rb * 64 +
                ((((ks >> 3) + quad) ^ (rb & 7)) * 8));
          }
#pragma unroll
          for (int i = 0; i < 2; i++)
#pragma unroll
            for (int j = 0; j < 4; j++)
              acc1[i][j] = __builtin_amdgcn_mfma_f32_16x16x32_bf16(af[i], bf[j], acc1[i][j], 0, 0, 0);
        }
        __builtin_amdgcn_s_barrier();
      }

      {
        float b1s[4];
#pragma unroll
        for (int j = 0; j < 4; j++)
          b1s[j] = b2f(GB1[c * 128 + wc * 64 + j * 16 + ln15]);
#pragma unroll
        for (int i = 0; i < 2; i++)
#pragma unroll
          for (int reg = 0; reg < 4; reg++) {
            const int rowl = wr * 32 + i * 16 + quad * 4 + reg;
#pragma unroll
            for (int j = 0; j < 4; j++) {
              const int coll = wc * 64 + j * 16 + ln15;
              tc[tca(rowl, coll)] = f2b(fmaxf(acc1[i][j][reg] + b1s[j], 0.f));
            }
          }
      }
      __syncthreads();

      for (int ks2 = 0; ks2 < 2; ks2++) {
#pragma unroll
        for (int i = 0; i < 8; i++) {
          const int fid = t + i * 256;
          const int row = fid >> 3;
          const int segp = (fid & 7) ^ (row & 7);
          glds16(GW2 + (size_t)row * 256 + c * 128 + ks2 * 64 + segp * 8,
                 shbuf + 24576 + fid * 8);
        }
        asm volatile("s_waitcnt vmcnt(0)" ::: "memory");
        __builtin_amdgcn_s_barrier();
#pragma unroll
        for (int ksl = 0; ksl < 64; ksl += 32) {
          s16x8 af[2], bf[8];
#pragma unroll
          for (int i = 0; i < 2; i++) {
            const int ra = wr * 32 + i * 16 + ln15;
            af[i] = *(const s16x8*)(&tc[tca(ra, ks2 * 64 + ksl + quad * 8)]);
          }
#pragma unroll
          for (int j = 0; j < 8; j++) {
            const int rb = wc * 128 + j * 16 + ln15;
            bf[j] = *(const s16x8*)(
                shbuf + 24576 + rb * 64 + ((((ksl >> 3) + quad) ^ (rb & 7)) * 8));
          }
#pragma unroll
          for (int i = 0; i < 2; i++)
#pragma unroll
            for (int j = 0; j < 8; j++)
              acc2[i][j] = __builtin_amdgcn_mfma_f32_16x16x32_bf16(af[i], bf[j], acc2[i][j], 0, 0, 0);
        }
        __builtin_amdgcn_s_barrier();
      }
    }

    float bs2[8];
#pragma unroll
    for (int j = 0; j < 8; j++)
      bs2[j] = b2f(GB2[wc * 128 + j * 16 + ln15]);

    float ssum[8] = {}, ssq[8] = {};
#pragma unroll
    for (int i = 0; i < 2; i++) {
#pragma unroll
      for (int reg = 0; reg < 4; reg++) {
        const int rowl = wr * 32 + i * 16 + quad * 4 + reg;
        const int row = row0 + rowl;
#pragma unroll
        for (int j = 0; j < 8; j++) {
          const int col = wc * 128 + j * 16 + ln15;
          float val = acc2[i][j][reg] + bs2[j];
          val += b2f(gres[tix(row, col)]);
          Cgin[tix(row, col)] = f2b(val);
          ssum[j] += val; ssq[j] += val * val;
        }
      }
    }

#pragma unroll
    for (int j = 0; j < 8; j++) {
      float s = ssum[j];
      s += __shfl_xor(s, 16);
      s += __shfl_xor(s, 32);
      float q = ssq[j];
      q += __shfl_xor(q, 16);
      q += __shfl_xor(q, 32);
      if (lane < 16) {
        atomicAdd(&gsum_l[wc * 128 + j * 16 + lane], s);
        atomicAdd(&gsq_l[wc * 128 + j * 16 + lane], q);
      }
    }
  } else {
    // ============ AO GEMM (r14 gemm_mfma<256,256,0,1,1,0,0> body) ============
    const int bid2 = blockIdx.x - 1024;
    const int col0 = (bid2 & 3) * 64;       // col fastest (r5 ordering)
    const int row0 = (bid2 >> 2) * 64;
    // As(b) = shbuf + b*4096; Bs(b) = shbuf + 8192 + b*4096

    f32x4 acc[2][2];
#pragma unroll
    for (int i = 0; i < 2; i++)
#pragma unroll
      for (int j = 0; j < 2; j++) acc[i][j] = (f32x4){0.f, 0.f, 0.f, 0.f};

    auto stage = [&](int b, int kt) {
      const u16* abase = Aao + ((size_t)(row0 >> 7) << 15) + ((kt >> 6) << 13) +
                         ((row0 & 64) << 6);
#pragma unroll
      for (int i = 0; i < 2; i++) {
        const int fid = t + i * 256;            // 0..511
        glds16(abase + fid * 8, shbuf + b * 4096 + fid * 8);
        const int row = fid >> 3;
        const int segp = (fid & 7) ^ (row & 7);
        glds16(AOW + (size_t)(col0 + row) * 256 + kt + segp * 8,
               shbuf + 8192 + b * 4096 + fid * 8);
      }
    };

    stage(0, 0);
    for (int kt = 0; kt < 256; kt += 64) {
      const int cur = (kt >> 6) & 1;
      if (kt + 64 < 256) {
        stage(cur ^ 1, kt + 64);
        asm volatile("s_waitcnt vmcnt(4)" ::: "memory");
      } else {
        asm volatile("s_waitcnt vmcnt(0)" ::: "memory");
      }
      __builtin_amdgcn_s_barrier();
#pragma unroll
      for (int ks = 0; ks < 64; ks += 32) {
        s16x8 af[2], bf[2];
#pragma unroll
        for (int i = 0; i < 2; i++) {
          const int ra = wr * 32 + i * 16 + ln15;
          af[i] = *(const s16x8*)(
              shbuf + cur * 4096 + ra * 64 + ((((ks >> 3) + quad) ^ (ra & 7)) * 8));
        }
#pragma unroll
        for (int j = 0; j < 2; j++) {
          const int rb = wc * 32 + j * 16 + ln15;
          bf[j] = *(const s16x8*)(
              shbuf + 8192 + cur * 4096 + rb * 64 + ((((ks >> 3) + quad) ^ (rb & 7)) * 8));
        }
#pragma unroll
        for (int i = 0; i < 2; i++)
#pragma unroll
          for (int j = 0; j < 2; j++)
            acc[i][j] = __builtin_amdgcn_mfma_f32_16x16x32_bf16(af[i], bf[j], acc[i][j], 0, 0, 0);
      }
      __builtin_amdgcn_s_barrier();
    }

    const int cbase = col0 + wc * 32;
    float bs[2];
#pragma unroll
    for (int j = 0; j < 2; j++) bs[j] = b2f(AOB[cbase + j * 16 + ln15]);

    float ssum[2] = {}, ssq[2] = {};
#pragma unroll
    for (int i = 0; i < 2; i++) {
      const int rbase = row0 + wr * 32 + i * 16 + quad * 4;
#pragma unroll
      for (int reg = 0; reg < 4; reg++) {
        const int row = rbase + reg;
#pragma unroll
        for (int j = 0; j < 2; j++) {
          float val = acc[i][j][reg] + bs[j];
          val += b2f(ares[tix(row, cbase + j * 16 + ln15)]);
          Cao[tix(row, cbase + j * 16 + ln15)] = f2b(val);
          ssum[j] += val; ssq[j] += val * val;
        }
      }
    }

#pragma unroll
    for (int j = 0; j < 2; j++) {
      float s = ssum[j];
      s += __shfl_xor(s, 16);
      s += __shfl_xor(s, 32);
      float q = ssq[j];
      q += __shfl_xor(q, 16);
      q += __shfl_xor(q, 32);
      if (lane < 16) {
        atomicAdd(&gsum_a[cbase + j * 16 + lane], s);
        atomicAdd(&gsq_a[cbase + j * 16 + lane], q);
      }
    }
  }
}

// ---------------------------------------------------------------------------
// Fused 2-layer MLP (r14 body; used for FFN only, COMBINE=1):
//   x = bn_l(A)+bn_a(Ara) with BN coefficients computed in-kernel;
//   C = x + relu(x@W1^T + b1)@W2^T + b2 (res from xs), + stats.
// LDS 80 KB -> 2 blocks/CU.
// ---------------------------------------------------------------------------
template <int CHUNKS, int RES_LDS, int COMBINE>
__global__ __launch_bounds__(256, 2) void fused_mlp(
    const u16* A, const u16* Ara,
    const u16* __restrict__ W1, const u16* __restrict__ b1,
    const u16* __restrict__ W2, const u16* __restrict__ b2,
    const u16* resg, u16* C, const float* __restrict__ st,
    const float* __restrict__ bn0g, const float* __restrict__ bn0b,
    const float* __restrict__ bn1g, const float* __restrict__ bn1b,
    float* __restrict__ gsum, float* __restrict__ gsq) {
  __shared__ u16 xs[4 * 64 * 64] __attribute__((aligned(16)));    // 32 KB
  __shared__ u16 tc[64 * 128] __attribute__((aligned(16)));       // 16 KB
  __shared__ u16 Wst[2][128 * 64] __attribute__((aligned(16)));   // 32 KB

  const int t = threadIdx.x;
  const int wave = t >> 6, lane = t & 63;
  const int wr = wave >> 1, wc = wave & 1;
  const int quad = lane >> 4, ln15 = lane & 15;
  const int row0 = blockIdx.x * 64;
  const int K2 = CHUNKS * 128;   // W2 row stride

  if (COMBINE) {
    float* cf = (float*)tc;
    {
      const float ml = st[t] * (1.f / R_);
      const float vl = fmaxf(st[256 + t] * (1.f / R_) - ml * ml, 0.f);
      const float al = bn0g[t] * rsqrtf(vl + 1e-5f);
      cf[t] = al;
      cf[256 + t] = bn0b[t] - ml * al;
      const float ma = st[512 + t] * (1.f / R_);
      const float va = fmaxf(st[768 + t] * (1.f / R_) - ma * ma, 0.f);
      const float aa = bn1g[t] * rsqrtf(va + 1e-5f);
      cf[512 + t] = aa;
      cf[768 + t] = bn1b[t] - ma * aa;
    }
    __syncthreads();
    const size_t tbase = ((size_t)(row0 >> 7) << 15) + ((row0 & 64) << 6);
#pragma unroll
    for (int i = 0; i < 8; i++) {
      const int gid = t + i * 256;
      const int kstep = gid >> 9;
      const int fid = gid & 511;
      const size_t addr = tbase + kstep * 8192 + fid * 8;
      const s16x8 rl = *(const s16x8*)(A + addr);
      const s16x8 ra = *(const s16x8*)(Ara + addr);
      const int seg = (fid & 7) ^ ((fid >> 3) & 7);
      const int col = kstep * 64 + seg * 8;
      const float4 al0 = *(const float4*)(cf + col);
      const float4 al1 = *(const float4*)(cf + col + 4);
      const float4 bl0 = *(const float4*)(cf + 256 + col);
      const float4 bl1 = *(const float4*)(cf + 256 + col + 4);
      const float4 aa0 = *(const float4*)(cf + 512 + col);
      const float4 aa1 = *(const float4*)(cf + 512 + col + 4);
      const float4 ba0 = *(const float4*)(cf + 768 + col);
      const float4 ba1 = *(const float4*)(cf + 768 + col + 4);
      const float al[8] = {al0.x, al0.y, al0.z, al0.w, al1.x, al1.y, al1.z, al1.w};
      const float bl[8] = {bl0.x, bl0.y, bl0.z, bl0.w, bl1.x, bl1.y, bl1.z, bl1.w};
      const float aa[8] = {aa0.x, aa0.y, aa0.z, aa0.w, aa1.x, aa1.y, aa1.z, aa1.w};
      const float ba[8] = {ba0.x, ba0.y, ba0.z, ba0.w, ba1.x, ba1.y, ba1.z, ba1.w};
      s16x8 o;
#pragma unroll
      for (int j = 0; j < 8; j++)
        o[j] = (short)f2b(al[j] * b2f((u16)rl[j]) + bl[j] +
                          aa[j] * b2f((u16)ra[j]) + ba[j]);
      *(s16x8*)(xs + gid * 8) = o;
    }
    __syncthreads();
  } else {
    const u16* abase = A + ((size_t)(row0 >> 7) << 15) + ((row0 & 64) << 6);
#pragma unroll
    for (int i = 0; i < 8; i++) {
      const int gid = t + i * 256;
      const int kstep = gid >> 9;
      const int fid = gid & 511;
      glds16(abase + kstep * 8192 + fid * 8, xs + gid * 8);
    }
  }

  f32x4 acc2[2][8];
#pragma unroll
  for (int i = 0; i < 2; i++)
#pragma unroll
    for (int j = 0; j < 8; j++) acc2[i][j] = (f32x4){0.f, 0.f, 0.f, 0.f};

  auto tca = [&](int row, int col) {
    const int s0 = col >> 3;
    return row * 128 + (((s0 & 8) | ((s0 ^ row) & 7)) << 3) + (col & 7);
  };

  for (int c = 0; c < CHUNKS; c++) {
    f32x4 acc1[2][4];
#pragma unroll
    for (int i = 0; i < 2; i++)
#pragma unroll
      for (int j = 0; j < 4; j++) acc1[i][j] = (f32x4){0.f, 0.f, 0.f, 0.f};

    auto stage1 = [&](int b, int kt) {
#pragma unroll
      for (int i = 0; i < 4; i++) {
        const int fid = t + i * 256;
        const int row = fid >> 3;
        const int segp = (fid & 7) ^ (row & 7);
        glds16(W1 + (size_t)(c * 128 + row) * 256 + kt + segp * 8,
               &Wst[b][fid * 8]);
      }
    };

    stage1(0, 0);
    for (int kt = 0; kt < 256; kt += 64) {
      const int cur = (kt >> 6) & 1;
      if (kt + 64 < 256) {
        stage1(cur ^ 1, kt + 64);
        asm volatile("s_waitcnt vmcnt(4)" ::: "memory");
      } else {
        asm volatile("s_waitcnt vmcnt(0)" ::: "memory");
      }
      __builtin_amdgcn_s_barrier();
#pragma unroll
      for (int ks = 0; ks < 64; ks += 32) {
        s16x8 af[2], bf[4];
#pragma unroll
        for (int i = 0; i < 2; i++) {
          const int ra = wr * 32 + i * 16 + ln15;
          af[i] = *(const s16x8*)(
              &xs[(kt >> 6) * 4096 + ra * 64 +
                  ((((ks >> 3) + quad) ^ (ra & 7)) * 8)]);
        }
#pragma unroll
        for (int j = 0; j < 4; j++) {
          const int rb = wc * 64 + j * 16 + ln15;
          bf[j] = *(const s16x8*)(
              &Wst[cur][rb * 64 + ((((ks >> 3) + quad) ^ (rb & 7)) * 8)]);
        }
#pragma unroll
        for (int i = 0; i < 2; i++)
#pragma unroll
          for (int j = 0; j < 4; j++)
            acc1[i][j] = __builtin_amdgcn_mfma_f32_16x16x32_bf16(af[i], bf[j], acc1[i][j], 0, 0, 0);
      }
      __builtin_amdgcn_s_barrier();
    }

    {
      float b1s[4];
#pragma unroll
      for (int j = 0; j < 4; j++)
        b1s[j] = b2f(b1[c * 128 + wc * 64 + j * 16 + ln15]);
#pragma unroll
      for (int i = 0; i < 2; i++)
#pragma unroll
        for (int reg = 0; reg < 4; reg++) {
          const int rowl = wr * 32 + i * 16 + quad * 4 + reg;
#pragma unroll
          for (int j = 0; j < 4; j++) {
            const int coll = wc * 64 + j * 16 + ln15;
            tc[tca(rowl, coll)] = f2b(fmaxf(acc1[i][j][reg] + b1s[j], 0.f));
          }
        }
    }
    __syncthreads();

    for (int ks2 = 0; ks2 < 2; ks2++) {
#pragma unroll
      for (int i = 0; i < 8; i++) {
        const int fid = t + i * 256;
        const int row = fid >> 3;
        const int segp = (fid & 7) ^ (row & 7);
        glds16(W2 + (size_t)row * K2 + c * 128 + ks2 * 64 + segp * 8,
               &Wst[0][fid * 8]);
      }
      asm volatile("s_waitcnt vmcnt(0)" ::: "memory");
      __builtin_amdgcn_s_barrier();
#pragma unroll
      for (int ksl = 0; ksl < 64; ksl += 32) {
        s16x8 af[2], bf[8];
#pragma unroll
        for (int i = 0; i < 2; i++) {
          const int ra = wr * 32 + i * 16 + ln15;
          af[i] = *(const s16x8*)(&tc[tca(ra, ks2 * 64 + ksl + quad * 8)]);
        }
#pragma unroll
        for (int j = 0; j < 8; j++) {
          const int rb = wc * 128 + j * 16 + ln15;
          bf[j] = *(const s16x8*)(
              &Wst[0][rb * 64 + ((((ksl >> 3) + quad) ^ (rb & 7)) * 8)]);
        }
#pragma unroll
        for (int i = 0; i < 2; i++)
#pragma unroll
          for (int j = 0; j < 8; j++)
            acc2[i][j] = __builtin_amdgcn_mfma_f32_16x16x32_bf16(af[i], bf[j], acc2[i][j], 0, 0, 0);
      }
      __builtin_amdgcn_s_barrier();
    }
  }

  float bs2[8];
#pragma unroll
  for (int j = 0; j < 8; j++)
    bs2[j] = b2f(b2[wc * 128 + j * 16 + ln15]);

  float ssum[8] = {}, ssq[8] = {};
#pragma unroll
  for (int i = 0; i < 2; i++) {
#pragma unroll
    for (int reg = 0; reg < 4; reg++) {
      const int rowl = wr * 32 + i * 16 + quad * 4 + reg;
      const int row = row0 + rowl;
#pragma unroll
      for (int j = 0; j < 8; j++) {
        const int col = wc * 128 + j * 16 + ln15;
        float val = acc2[i][j][reg] + bs2[j];
        if (RES_LDS) {
          val += b2f(xs[(col >> 6) * 4096 + rowl * 64 +
                        ((((col >> 3) & 7) ^ (rowl & 7)) << 3) + (col & 7)]);
        } else {
          val += b2f(resg[tix(row, col)]);
        }
        C[tix(row, col)] = f2b(val);
        ssum[j] += val; ssq[j] += val * val;
      }
    }
  }

#pragma unroll
  for (int j = 0; j < 8; j++) {
    float s = ssum[j];
    s += __shfl_xor(s, 16);
    s += __shfl_xor(s, 32);
    float q = ssq[j];
    q += __shfl_xor(q, 16);
    q += __shfl_xor(q, 32);
    if (lane < 16) {
      atomicAdd(&gsum[wc * 128 + j * 16 + lane], s);
      atomicAdd(&gsq[wc * 128 + j * 16 + lane], q);
    }
  }
}

// out = bn_out(y) with bn_finalize folded: per-thread coefficient compute.
__global__ __launch_bounds__(256) void final_kernel(
    const u16* __restrict__ y, const float* __restrict__ st,
    const float* __restrict__ bg, const float* __restrict__ bb,
    float* __restrict__ out) {
  const int e = (blockIdx.x * 256 + threadIdx.x) * 4;
  const int col = e & 255;
  float y4[4];
  ld4b(y + tix(e >> 8, col), y4);
  const float4 s4 = *(const float4*)(st + 1024 + col);
  const float4 q4 = *(const float4*)(st + 1280 + col);
  const float4 g4 = *(const float4*)(bg + col);
  const float4 b4 = *(const float4*)(bb + col);
  const float ss[4] = {s4.x, s4.y, s4.z, s4.w};
  const float qq[4] = {q4.x, q4.y, q4.z, q4.w};
  const float gg[4] = {g4.x, g4.y, g4.z, g4.w};
  const float bv[4] = {b4.x, b4.y, b4.z, b4.w};
  float4 o;
  float* ov = (float*)&o;
#pragma unroll
  for (int j = 0; j < 4; j++) {
    const float mean = ss[j] * (1.f / R_);
    const float var = fmaxf(qq[j] * (1.f / R_) - mean * mean, 0.f);
    const float a = gg[j] * rsqrtf(var + 1e-5f);
    ov[j] = a * y4[j] + (bv[j] - mean * a);
  }
  *(float4*)(out + e) = o;
}

extern "C" void kernel_launch(void* const* d_in, const int* in_sizes, int n_in,
                              void* d_out, int out_size, void* d_ws, size_t ws_size,
                              hipStream_t stream) {
  const float* h = (const float*)d_in[0];
  const int* esrc = (const int*)d_in[1];
  const int* edst = (const int*)d_in[2];
  const float* bn_local_g = (const float*)d_in[11];
  const float* bn_local_b = (const float*)d_in[12];
  const float* bn_attn_g = (const float*)d_in[13];
  const float* bn_attn_b = (const float*)d_in[14];
  const float* bn_out_g = (const float*)d_in[15];
  const float* bn_out_b = (const float*)d_in[16];

  const size_t RH = (size_t)R_ * H_;
  float* stats = (float*)d_ws;                        // 1536 floats used
  u16* WB = (u16*)((char*)d_ws + 65536);              // packed bf16 weights ~1.3 MB
  u16* Hb = (u16*)((char*)d_ws + 65536 + 2097152);    // h in bf16 (tiled), 32 MB
  u16* S1 = Hb + RH;                                  // 32 MB
  u16* S2 = S1 + RH;                                  // 32 MB
  u16* OD = (u16*)d_out;                              // bytes 0..32MB of d_out
  u16* OD2 = OD + RH;                                 // bytes 32..64MB of d_out
  float* outf = (float*)d_out;                        // final fp32 out (64 MB)

  // cvt_h + cvt_w + zero_stats in one launch
  prep_kernel<<<16384 + 643 + 12, 256, 0, stream>>>(
      h, Hb,
      (const float*)d_in[3], (const float*)d_in[4], (const float*)d_in[5],
      (const float*)d_in[6], (const float*)d_in[7], (const float*)d_in[8],
      (const float*)d_in[9], (const float*)d_in[10], (const float*)d_in[17],
      (const float*)d_in[18], (const float*)d_in[19], (const float*)d_in[20],
      WB, stats);

  // qkv: A staged once per block for all of q,k,v -> q=S1, k=S2, v=OD
  qkv_mfma<<<dim3(4, 1024), 256, 0, stream>>>(
      Hb, WB + OFF_AIW, WB + OFF_AIB, S1, S2, OD);
  // attn (o -> S1 in place) || agg (z = h + segsum -> OD2): independent
  attn_agg<<<4096 + 2048, 256, 0, stream>>>(
      S1, S2, OD, S1, Hb, esrc, edst, OD2);
  // GIN MLP (r_local = h + MLP(z) -> OD, stats_local) ||
  // AO GEMM (r_attn = h + o@Wo^T -> S2, stats_attn): independent
  gin_ao<<<1024 + 4096, 256, 0, stream>>>(
      OD2, Hb, WB + OFF_GW1, WB + OFF_GB1, WB + OFF_GW2, WB + OFF_GB2,
      OD, stats + 0, stats + 256,
      S1, WB + OFF_AOW, WB + OFF_AOB, Hb, S2, stats + 512, stats + 768);
  // y = x + relu(x@F1+b1)@F2+b2 -> S1; x = bn_l(OD)+bn_a(S2) computed in the
  // x-stage (combine + bn_finalize folds), + stats_out
  fused_mlp<4, 1, 1><<<1024, 256, 0, stream>>>(
      OD, S2,
      WB + OFF_F1W, WB + OFF_F1B, WB + OFF_F2W, WB + OFF_F2B,
      nullptr, S1, stats, bn_local_g, bn_local_b, bn_attn_g, bn_attn_b,
      stats + 1024, stats + 1280);
  // out = bn_out(y S1) -> fp32 d_out (bn_finalize folded)
  final_kernel<<<(int)(RH / 4 / 256), 256, 0, stream>>>(
      S1, stats, bn_out_g, bn_out_b, outf);
}